// Round 7
// baseline (1306.135 us; speedup 1.0000x reference)
//
#include <hip/hip_runtime.h>

#define N_USERS 40000
#define N_POIS  20000
#define DIM     128
#define N_EDGES 500000
#define BATCH   256
#define NPOS    100
#define TOPK    20
#define NCHUNK  256
#define CPT     157   // ceil(40000/256)

__device__ __forceinline__ int iclamp(int x, int lo, int hi) {
    return x < lo ? lo : (x > hi ? hi : x);
}
__device__ __forceinline__ float softmax3(const float* p, int sel) {
    float a0 = p[0], a1 = p[1], a2 = p[2];
    float m = fmaxf(a0, fmaxf(a1, a2));
    float e0 = expf(a0 - m), e1 = expf(a1 - m), e2 = expf(a2 - m);
    float den = e0 + e1 + e2;
    float e = (sel == 0) ? e0 : ((sel == 1) ? e1 : e2);
    return e / den;
}

// ---------------- zero init ----------------
__global__ void zero_kernel(unsigned int* __restrict__ p, int nwords) {
    int i = blockIdx.x * blockDim.x + threadIdx.x;
    if (i < nwords) p[i] = 0u;
}

// ---------------- CSR build ----------------
__global__ void hist_kernel(const int* __restrict__ er, const int* __restrict__ ec,
                            int* __restrict__ rcnt, int* __restrict__ ccnt) {
    int e = blockIdx.x * blockDim.x + threadIdx.x;
    if (e < N_EDGES) {
        atomicAdd(&rcnt[iclamp(er[e], 0, N_USERS - 1)], 1);
        atomicAdd(&ccnt[iclamp(ec[e], 0, N_POIS - 1)], 1);
    }
}

__global__ void scan_kernel(const int* __restrict__ rcnt, int* __restrict__ rptr,
                            const int* __restrict__ ccnt, int* __restrict__ cptr) {
    const int* cnt = blockIdx.x ? ccnt : rcnt;
    int* ptr = blockIdx.x ? cptr : rptr;
    int n = blockIdx.x ? N_POIS : N_USERS;
    __shared__ int part[256];
    __shared__ int pref[257];
    int C = (n + 255) / 256;
    int lo = threadIdx.x * C;
    int hi = lo + C; if (hi > n) hi = n;
    int s = 0;
    for (int i = lo; i < hi; i++) s += cnt[i];
    part[threadIdx.x] = s;
    __syncthreads();
    if (threadIdx.x == 0) {
        int r = 0;
        for (int i = 0; i < 256; i++) { pref[i] = r; r += part[i]; }
        pref[256] = r;
    }
    __syncthreads();
    int r = pref[threadIdx.x];
    for (int i = lo; i < hi; i++) { ptr[i] = r; r += cnt[i]; }
    if (threadIdx.x == 0) ptr[n] = pref[256];
}

// fill CSR topology + gather all 3 channels' vals into CSR order (both directions)
__global__ void fill_kernel(const int* __restrict__ er, const int* __restrict__ ec,
                            const int* __restrict__ rptr, const int* __restrict__ cptr,
                            int* __restrict__ rcur, int* __restrict__ ccur,
                            int* __restrict__ rcols, int* __restrict__ crows,
                            const float* __restrict__ ck, const float* __restrict__ fv,
                            const float* __restrict__ cs,
                            float* __restrict__ rv0, float* __restrict__ rv1, float* __restrict__ rv2,
                            float* __restrict__ cv0, float* __restrict__ cv1, float* __restrict__ cv2) {
    int e = blockIdx.x * blockDim.x + threadIdx.x;
    if (e < N_EDGES) {
        int r = iclamp(er[e], 0, N_USERS - 1), c = iclamp(ec[e], 0, N_POIS - 1);
        float v0 = ck[e], v1 = fv[e], v2 = cs[e];
        int pr = iclamp(rptr[r] + atomicAdd(&rcur[r], 1), 0, N_EDGES - 1);
        rcols[pr] = c; rv0[pr] = v0; rv1[pr] = v1; rv2[pr] = v2;
        int pc = iclamp(cptr[c] + atomicAdd(&ccur[c], 1), 0, N_EDGES - 1);
        crows[pc] = r; cv0[pc] = v0; cv1[pc] = v1; cv2[pc] = v2;
    }
}

// ---------------- SpMM: one wave per row; CSR-ordered vals; unroll x8 ----------------
__global__ __launch_bounds__(256) void spmm_kernel(
        const int* __restrict__ ptr, const int* __restrict__ nbr,
        const float* __restrict__ vals,   // CSR-ordered
        const float* __restrict__ src, int srows,
        float* __restrict__ raw,
        const float* __restrict__ base,   // may alias acc
        float* __restrict__ acc, int nrows) {
    int wid = (blockIdx.x * blockDim.x + threadIdx.x) >> 6;
    int lane = threadIdx.x & 63;
    if (wid >= nrows) return;
    int beg = __builtin_amdgcn_readfirstlane(iclamp(ptr[wid], 0, N_EDGES));
    int end = __builtin_amdgcn_readfirstlane(iclamp(ptr[wid + 1], 0, N_EDGES));
    if (end < beg) end = beg;
    float ax = 0.f, ay = 0.f;
    int e = beg;
    int lo2 = lane * 2;
    for (; e + 8 <= end; e += 8) {
        int c0 = nbr[e + 0], c1 = nbr[e + 1], c2 = nbr[e + 2], c3 = nbr[e + 3];
        int c4 = nbr[e + 4], c5 = nbr[e + 5], c6 = nbr[e + 6], c7 = nbr[e + 7];
        float v0 = vals[e + 0], v1 = vals[e + 1], v2 = vals[e + 2], v3 = vals[e + 3];
        float v4 = vals[e + 4], v5 = vals[e + 5], v6 = vals[e + 6], v7 = vals[e + 7];
        float2 p0 = *(const float2*)(src + (size_t)c0 * DIM + lo2);
        float2 p1 = *(const float2*)(src + (size_t)c1 * DIM + lo2);
        float2 p2 = *(const float2*)(src + (size_t)c2 * DIM + lo2);
        float2 p3 = *(const float2*)(src + (size_t)c3 * DIM + lo2);
        float2 p4 = *(const float2*)(src + (size_t)c4 * DIM + lo2);
        float2 p5 = *(const float2*)(src + (size_t)c5 * DIM + lo2);
        float2 p6 = *(const float2*)(src + (size_t)c6 * DIM + lo2);
        float2 p7 = *(const float2*)(src + (size_t)c7 * DIM + lo2);
        ax = fmaf(v0, p0.x, fmaf(v1, p1.x, fmaf(v2, p2.x, fmaf(v3, p3.x, ax))));
        ax = fmaf(v4, p4.x, fmaf(v5, p5.x, fmaf(v6, p6.x, fmaf(v7, p7.x, ax))));
        ay = fmaf(v0, p0.y, fmaf(v1, p1.y, fmaf(v2, p2.y, fmaf(v3, p3.y, ay))));
        ay = fmaf(v4, p4.y, fmaf(v5, p5.y, fmaf(v6, p6.y, fmaf(v7, p7.y, ay))));
    }
    for (; e + 4 <= end; e += 4) {
        int c0 = nbr[e + 0], c1 = nbr[e + 1], c2 = nbr[e + 2], c3 = nbr[e + 3];
        float v0 = vals[e + 0], v1 = vals[e + 1], v2 = vals[e + 2], v3 = vals[e + 3];
        float2 p0 = *(const float2*)(src + (size_t)c0 * DIM + lo2);
        float2 p1 = *(const float2*)(src + (size_t)c1 * DIM + lo2);
        float2 p2 = *(const float2*)(src + (size_t)c2 * DIM + lo2);
        float2 p3 = *(const float2*)(src + (size_t)c3 * DIM + lo2);
        ax = fmaf(v0, p0.x, fmaf(v1, p1.x, fmaf(v2, p2.x, fmaf(v3, p3.x, ax))));
        ay = fmaf(v0, p0.y, fmaf(v1, p1.y, fmaf(v2, p2.y, fmaf(v3, p3.y, ay))));
    }
    for (; e < end; e++) {
        int c = nbr[e];
        float v = vals[e];
        float2 pv = *(const float2*)(src + (size_t)c * DIM + lo2);
        ax = fmaf(v, pv.x, ax);
        ay = fmaf(v, pv.y, ay);
    }
    float n2 = ax * ax + ay * ay;
    #pragma unroll
    for (int o = 32; o > 0; o >>= 1) n2 += __shfl_xor(n2, o, 64);
    float inv = rsqrtf(fmaxf(n2, 1e-30f));
    *(float2*)(raw + (size_t)wid * DIM + lo2) = make_float2(ax, ay);
    float2 bv = *(const float2*)(base + (size_t)wid * DIM + lo2);
    *(float2*)(acc + (size_t)wid * DIM + lo2) =
        make_float2(bv.x + ax * inv, bv.y + ay * inv);
}

// ---------------- out = A[Mx128] @ W^T ; A-tile (32 rows) in LDS, W rows from global ----------------
__global__ __launch_bounds__(256) void gemm_aw_kernel(
        const float* __restrict__ A, const float* __restrict__ W,
        float* __restrict__ store, float* __restrict__ accum,
        const float* __restrict__ fw3, int fsel, int first, int M) {
    __shared__ float Al[32 * 128];                 // 16 KB
    int i0 = blockIdx.x * 32;
    const float4* Ag = (const float4*)(A + (size_t)i0 * DIM);
    float4* Al4 = (float4*)Al;
    for (int qi = threadIdx.x; qi < 1024; qi += 256) Al4[qi] = Ag[qi];
    __syncthreads();
    float coef = accum ? softmax3(fw3, fsel) : 0.f;
    int j2 = threadIdx.x & 63;                     // cols j2 and j2+64
    int rg = threadIdx.x >> 6;                     // rows rg + 4*m, m=0..7
    const float4* W0 = (const float4*)(W + (size_t)j2 * DIM);
    const float4* W1 = (const float4*)(W + (size_t)(j2 + 64) * DIM);
    float acc0[8], acc1[8];
    #pragma unroll
    for (int m = 0; m < 8; m++) { acc0[m] = 0.f; acc1[m] = 0.f; }
    for (int kq = 0; kq < 32; kq++) {
        float4 w0 = W0[kq];
        float4 w1 = W1[kq];
        #pragma unroll
        for (int m = 0; m < 8; m++) {
            float4 a = Al4[(rg + 4 * m) * 32 + kq];   // broadcast within wave
            acc0[m] = fmaf(a.x, w0.x, acc0[m]); acc0[m] = fmaf(a.y, w0.y, acc0[m]);
            acc0[m] = fmaf(a.z, w0.z, acc0[m]); acc0[m] = fmaf(a.w, w0.w, acc0[m]);
            acc1[m] = fmaf(a.x, w1.x, acc1[m]); acc1[m] = fmaf(a.y, w1.y, acc1[m]);
            acc1[m] = fmaf(a.z, w1.z, acc1[m]); acc1[m] = fmaf(a.w, w1.w, acc1[m]);
        }
    }
    #pragma unroll
    for (int m = 0; m < 8; m++) {
        int i = i0 + rg + 4 * m;
        if (i >= M) continue;
        size_t o0 = (size_t)i * DIM + j2;
        size_t o1 = o0 + 64;
        if (store) { store[o0] = acc0[m]; store[o1] = acc1[m]; }
        if (accum) {
            float p0 = first ? 0.f : accum[o0];
            float p1 = first ? 0.f : accum[o1];
            accum[o0] = p0 + coef * acc0[m];
            accum[o1] = p1 + coef * acc1[m];
        }
    }
}

// ---------------- 256 selected rows of uf = su @ Wu^T ----------------
__global__ void ufsel_kernel(const float* __restrict__ su, const float* __restrict__ W,
                             const int* __restrict__ uidx, float* __restrict__ outsel) {
    int b = blockIdx.x, j = threadIdx.x;  // block 128
    __shared__ float ar[128];
    int u = iclamp(uidx[b], 0, N_USERS - 1);
    ar[j] = su[(size_t)u * DIM + j];
    __syncthreads();
    const float4* Wr = (const float4*)(W + (size_t)j * DIM);
    float acc = 0.f;
    #pragma unroll 8
    for (int q = 0; q < 32; q++) {
        float4 wq = Wr[q];
        acc = fmaf(ar[4 * q + 0], wq.x, acc);
        acc = fmaf(ar[4 * q + 1], wq.y, acc);
        acc = fmaf(ar[4 * q + 2], wq.z, acc);
        acc = fmaf(ar[4 * q + 3], wq.w, acc);
    }
    outsel[(size_t)b * DIM + j] = acc;
}

// ---------------- alt[b,j] += wn_c * dot(uf_c[b], pf_c[poi]) ----------------
__global__ __launch_bounds__(256) void predict_kernel(
        const float* __restrict__ ufs, const float* __restrict__ pf,
        const int* __restrict__ pidx, const float* __restrict__ w3,
        int wsel, float* __restrict__ alt) {
    int wid = (blockIdx.x * blockDim.x + threadIdx.x) >> 6;
    int lane = threadIdx.x & 63;
    if (wid >= BATCH * NPOS) return;
    int b = wid / NPOS;
    int poi = iclamp(pidx[wid], 0, N_POIS - 1);
    const float2 uv = *(const float2*)(ufs + (size_t)b * DIM + lane * 2);
    const float2 pv = *(const float2*)(pf + (size_t)poi * DIM + lane * 2);
    float s = uv.x * pv.x + uv.y * pv.y;
    #pragma unroll
    for (int o = 32; o > 0; o >>= 1) s += __shfl_xor(s, o, 64);
    if (lane == 0) {
        float coef = softmax3(w3, wsel);
        alt[wid] += coef * s;
    }
}

// ---------------- BCE loss ----------------
__global__ void loss_kernel(const float* __restrict__ alt, const float* __restrict__ labels,
                            float* __restrict__ out) {
    __shared__ float red[256];
    float s = 0.f;
    for (int i = threadIdx.x; i < BATCH * NPOS; i += 256) {
        float x = alt[i], y = labels[i];
        s += fmaxf(x, 0.f) - x * y + log1pf(expf(-fabsf(x)));
    }
    red[threadIdx.x] = s;
    __syncthreads();
    for (int off = 128; off > 0; off >>= 1) {
        if (threadIdx.x < off) red[threadIdx.x] += red[threadIdx.x + off];
        __syncthreads();
    }
    if (threadIdx.x == 0) out[0] = red[0] / (float)(BATCH * NPOS);
}

// ---------------- bst[j][b] = id_feat[cur[b]] @ Ws^T + bias (transposed) ----------------
__global__ void bs_kernel(const float* __restrict__ idf, const float* __restrict__ Ws,
                          const float* __restrict__ bias, const int* __restrict__ uidx,
                          float* __restrict__ bst) {
    int b = blockIdx.x, j = threadIdx.x;  // block 128
    __shared__ float ar[128];
    int u = iclamp(uidx[b], 0, N_USERS - 1);
    ar[j] = idf[(size_t)u * DIM + j];
    __syncthreads();
    const float4* Wr = (const float4*)(Ws + (size_t)j * DIM);
    float acc = 0.f;
    #pragma unroll 8
    for (int q = 0; q < 32; q++) {
        float4 wq = Wr[q];
        acc = fmaf(ar[4 * q + 0], wq.x, acc);
        acc = fmaf(ar[4 * q + 1], wq.y, acc);
        acc = fmaf(ar[4 * q + 2], wq.z, acc);
        acc = fmaf(ar[4 * q + 3], wq.w, acc);
    }
    bst[(size_t)j * BATCH + b] = acc + bias[j];
}

__device__ __forceinline__ void topk_insert(float s, int u, float* ts, int* ti) {
    if (s > ts[TOPK - 1]) {
        #pragma unroll
        for (int j = TOPK - 1; j > 0; --j) {
            bool above = s > ts[j - 1];
            bool here = (!above) && (s > ts[j]);
            float nv = above ? ts[j - 1] : (here ? s : ts[j]);
            int ni = above ? ti[j - 1] : (here ? u : ti[j]);
            ts[j] = nv; ti[j] = ni;
        }
        if (s > ts[0]) { ts[0] = s; ti[0] = u; }
    }
}

// ---------------- fused uu scores + per-block top-20: [q][b][4] LDS (b128), 4 users/thread ----------------
__global__ __launch_bounds__(256) void score_topk_kernel(
        const float* __restrict__ idf, const float* __restrict__ bst,
        float* __restrict__ cand_s, int* __restrict__ cand_i) {
    __shared__ __align__(16) unsigned char smraw[40960];
    float* bsl = (float*)smraw;           // phase 1: [q][b][4] = 32x64x4 floats (32 KB)
    float* ms  = (float*)smraw;           // phase 2: [k][tid] 20x256 floats (20 KB)
    int*   mi  = (int*)(smraw + 20480);   // phase 2: [k][tid] 20x256 ints  (20 KB)
    int cid = blockIdx.x, bg = blockIdx.y;
    // stage: bsl[(q*64+b)*4 + j] = bst[(4q+j)*BATCH + bg*64 + b]; coalesced global, b128 LDS write
    for (int idx = threadIdx.x; idx < 32 * 64; idx += 256) {
        int b = idx & 63, q = idx >> 6;
        float4 v;
        v.x = bst[(size_t)(4 * q + 0) * BATCH + bg * 64 + b];
        v.y = bst[(size_t)(4 * q + 1) * BATCH + bg * 64 + b];
        v.z = bst[(size_t)(4 * q + 2) * BATCH + bg * 64 + b];
        v.w = bst[(size_t)(4 * q + 3) * BATCH + bg * 64 + b];
        *(float4*)&bsl[(size_t)idx * 4] = v;
    }
    __syncthreads();
    int b_l = threadIdx.x & 63, us = threadIdx.x >> 6;
    const float4* bcol = (const float4*)&bsl[b_l * 4];   // stride 64 float4s between q
    float ts[TOPK]; int ti[TOPK];
    #pragma unroll
    for (int k = 0; k < TOPK; k++) { ts[k] = -3.0e38f; ti[k] = 0; }
    int lo = cid * CPT;
    int hi = lo + CPT; if (hi > N_USERS) hi = N_USERS;
    for (int u0 = lo + us * 4; u0 < hi; u0 += 16) {
        int uc1 = u0 + 1 < N_USERS ? u0 + 1 : N_USERS - 1;
        int uc2 = u0 + 2 < N_USERS ? u0 + 2 : N_USERS - 1;
        int uc3 = u0 + 3 < N_USERS ? u0 + 3 : N_USERS - 1;
        const float4* r0 = (const float4*)(idf + (size_t)u0 * DIM);
        const float4* r1 = (const float4*)(idf + (size_t)uc1 * DIM);
        const float4* r2 = (const float4*)(idf + (size_t)uc2 * DIM);
        const float4* r3 = (const float4*)(idf + (size_t)uc3 * DIM);
        float s0 = 0.f, s1 = 0.f, s2 = 0.f, s3 = 0.f;
        #pragma unroll 8
        for (int q = 0; q < 32; q++) {
            float4 bb = bcol[q * 64];                  // one ds_read_b128, conflict-free
            float4 a0 = r0[q], a1 = r1[q], a2 = r2[q], a3 = r3[q];
            s0 = fmaf(a0.x, bb.x, fmaf(a0.y, bb.y, fmaf(a0.z, bb.z, fmaf(a0.w, bb.w, s0))));
            s1 = fmaf(a1.x, bb.x, fmaf(a1.y, bb.y, fmaf(a1.z, bb.z, fmaf(a1.w, bb.w, s1))));
            s2 = fmaf(a2.x, bb.x, fmaf(a2.y, bb.y, fmaf(a2.z, bb.z, fmaf(a2.w, bb.w, s2))));
            s3 = fmaf(a3.x, bb.x, fmaf(a3.y, bb.y, fmaf(a3.z, bb.z, fmaf(a3.w, bb.w, s3))));
        }
        topk_insert(s0, u0, ts, ti);
        if (u0 + 1 < hi) topk_insert(s1, u0 + 1, ts, ti);
        if (u0 + 2 < hi) topk_insert(s2, u0 + 2, ts, ti);
        if (u0 + 3 < hi) topk_insert(s3, u0 + 3, ts, ti);
    }
    __syncthreads();
    // transposed merge scratch: ms[k*256 + tid] — lanes consecutive -> conflict-free
    #pragma unroll
    for (int k = 0; k < TOPK; k++) {
        ms[k * 256 + threadIdx.x] = ts[k];
        mi[k * 256 + threadIdx.x] = ti[k];
    }
    __syncthreads();
    if (threadIdx.x < 64) {
        int t = threadIdx.x;
        int p0 = 0, p1 = 0, p2 = 0, p3 = 0;
        size_t ob = (((size_t)cid) * 256 + bg * 64 + t) * TOPK;
        for (int k = 0; k < TOPK; k++) {
            float h0 = ms[p0 * 256 + 0 * 64 + t];
            float h1 = ms[p1 * 256 + 1 * 64 + t];
            float h2 = ms[p2 * 256 + 2 * 64 + t];
            float h3 = ms[p3 * 256 + 3 * 64 + t];
            float best = h0; int which = 0;
            if (h1 > best) { best = h1; which = 1; }
            if (h2 > best) { best = h2; which = 2; }
            if (h3 > best) { best = h3; which = 3; }
            int idx;
            if (which == 0)      { idx = mi[p0 * 256 + 0 * 64 + t]; p0++; }
            else if (which == 1) { idx = mi[p1 * 256 + 1 * 64 + t]; p1++; }
            else if (which == 2) { idx = mi[p2 * 256 + 2 * 64 + t]; p2++; }
            else                 { idx = mi[p3 * 256 + 3 * 64 + t]; p3++; }
            cand_s[ob + k] = best;
            cand_i[ob + k] = idx;
        }
    }
}

// ---------------- global merge (256 chunks) + softmax + weighted gather ----------------
__global__ void topk_merge_kernel(const float* __restrict__ cand_s, const int* __restrict__ cand_i,
                                  const float* __restrict__ guf,
                                  float* __restrict__ outp) {
    int b = blockIdx.x, t = threadIdx.x;  // block 256 (= NCHUNK)
    __shared__ float rs[256]; __shared__ int ru[256]; __shared__ int rt[256];
    __shared__ float win_s[TOPK]; __shared__ int win_u[TOPK]; __shared__ float wk[TOPK];
    __shared__ int winner;
    int ptr = 0;
    size_t base = ((size_t)t * 256 + b) * TOPK;
    for (int k = 0; k < TOPK; k++) {
        rs[t] = (ptr < TOPK) ? cand_s[base + ptr] : -3.0e38f;
        ru[t] = (ptr < TOPK) ? cand_i[base + ptr] : 0;
        rt[t] = t;
        __syncthreads();
        for (int off = 128; off > 0; off >>= 1) {
            if (t < off && rs[t + off] > rs[t]) {
                rs[t] = rs[t + off]; ru[t] = ru[t + off]; rt[t] = rt[t + off];
            }
            __syncthreads();
        }
        if (t == 0) { win_s[k] = rs[0]; win_u[k] = iclamp(ru[0], 0, N_USERS - 1); winner = rt[0]; }
        __syncthreads();
        if (t == winner) ptr++;
        __syncthreads();
    }
    if (t == 0) {
        float m = win_s[0], den = 0.f;
        for (int k = 0; k < TOPK; k++) { wk[k] = expf(win_s[k] - m); den += wk[k]; }
        float inv = 1.f / den;
        for (int k = 0; k < TOPK; k++) wk[k] *= inv;
    }
    __syncthreads();
    if (t < DIM) {
        float acc = 0.f;
        #pragma unroll
        for (int k = 0; k < TOPK; k++)
            acc = fmaf(wk[k], guf[(size_t)win_u[k] * DIM + t], acc);
        outp[1 + (size_t)b * DIM + t] = acc;
    }
}

extern "C" void kernel_launch(void* const* d_in, const int* in_sizes, int n_in,
                              void* d_out, int out_size, void* d_ws, size_t ws_size,
                              hipStream_t stream) {
    (void)in_sizes; (void)n_in; (void)out_size; (void)ws_size;
    const int*   er      = (const int*)d_in[0];
    const int*   ec      = (const int*)d_in[1];
    const float* click   = (const float*)d_in[2];
    const float* favor   = (const float*)d_in[3];
    const float* consume = (const float*)d_in[4];
    const float* uid     = (const float*)d_in[5];
    const float* pid     = (const float*)d_in[6];
    const int*   uidx    = (const int*)d_in[7];
    const int*   pidx    = (const int*)d_in[8];
    const float* labels  = (const float*)d_in[9];
    const float* guf     = (const float*)d_in[10];
    const float* w3      = (const float*)d_in[11];
    const float* fw3     = (const float*)d_in[12];
    const float* Wuc     = (const float*)d_in[13];
    const float* Wpc     = (const float*)d_in[14];
    const float* Wufv    = (const float*)d_in[15];
    const float* Wpfv    = (const float*)d_in[16];
    const float* Wuco    = (const float*)d_in[17];
    const float* Wpco    = (const float*)d_in[18];
    const float* Wss     = (const float*)d_in[19];
    const float* bias    = (const float*)d_in[20];
    float* outp = (float*)d_out;

    char* ws = (char*)d_ws;
    size_t off = 0;
    auto carve = [&](size_t bytes) -> void* {
        off = (off + 255) & ~(size_t)255;
        void* p = ws + off;
        off += bytes;
        return p;
    };
    float* ufs = (float*)carve(4ll * 3 * BATCH * DIM);
    float* alt = (float*)carve(4ll * BATCH * NPOS);
    float* bst = (float*)carve(4ll * DIM * BATCH);     // transposed bs [k][b]
    int* rptr = (int*)carve(4 * (N_USERS + 1));
    int* cptr = (int*)carve(4 * (N_POIS + 1));
    int* cnts = (int*)carve(4 * (2 * (N_USERS + N_POIS)));
    int* rcnt = cnts;
    int* ccnt = cnts + N_USERS;
    int* rcur = ccnt + N_POIS;
    int* ccur = rcur + N_USERS;
    int* rcols = (int*)carve(4 * (size_t)N_EDGES);
    int* crows = (int*)carve(4 * (size_t)N_EDGES);
    float* rv[3]; float* cv[3];
    for (int c = 0; c < 3; c++) rv[c] = (float*)carve(4 * (size_t)N_EDGES);
    for (int c = 0; c < 3; c++) cv[c] = (float*)carve(4 * (size_t)N_EDGES);
    float* utr  = (float*)carve(4ll * N_USERS * DIM);   // raw u ; pf alias
    float* ptr_ = (float*)carve(4ll * N_POIS * DIM);    // raw p
    float* su   = (float*)carve(4ll * N_USERS * DIM);   // cand alias (needs 10.5 MB <= 20.5 MB)
    float* sp   = (float*)carve(4ll * N_POIS * DIM);
    float* idf  = (float*)carve(4ll * N_USERS * DIM);
    float* pf = utr;                                    // utr dead before pf written
    float* cand_s = su;                                 // su dead before score_topk
    int*   cand_i = (int*)(su + (size_t)NCHUNK * BATCH * TOPK);

    zero_kernel<<<(2 * (N_USERS + N_POIS) + 255) / 256, 256, 0, stream>>>((unsigned int*)cnts, 2 * (N_USERS + N_POIS));
    zero_kernel<<<(BATCH * NPOS + 255) / 256, 256, 0, stream>>>((unsigned int*)alt, BATCH * NPOS);

    hist_kernel<<<(N_EDGES + 255) / 256, 256, 0, stream>>>(er, ec, rcnt, ccnt);
    scan_kernel<<<2, 256, 0, stream>>>(rcnt, rptr, ccnt, cptr);
    fill_kernel<<<(N_EDGES + 255) / 256, 256, 0, stream>>>(
        er, ec, rptr, cptr, rcur, ccur, rcols, crows,
        click, favor, consume, rv[0], rv[1], rv[2], cv[0], cv[1], cv[2]);

    struct Ch { const float* Wu; const float* Wp; int wsel; int fsel; };
    // wn (softmax over w[1,3]):  favor=0, click=1, consume=2
    // fwn (softmax over fw[3,1]): favor=0, consume=1, click=2
    Ch chs[3] = { { Wuc,  Wpc,  1, 2 },     // rv[0]/cv[0] = click
                  { Wufv, Wpfv, 0, 0 },     // rv[1]/cv[1] = favor
                  { Wuco, Wpco, 2, 1 } };   // rv[2]/cv[2] = consume

    for (int c = 0; c < 3; c++) {
        // layer 1: u1 = A p0 ; su = uid + n(u1).  p1 = A^T u1 ; sp = pid + n(p1)
        spmm_kernel<<<N_USERS * 64 / 256, 256, 0, stream>>>(rptr, rcols, rv[c], pid, N_POIS, utr, uid, su, N_USERS);
        spmm_kernel<<<N_POIS * 64 / 256, 256, 0, stream>>>(cptr, crows, cv[c], utr, N_USERS, ptr_, pid, sp, N_POIS);
        // layer 2: u2 = A p1 ; su += n(u2).  p2 = A^T u2 ; sp += n(p2)
        spmm_kernel<<<N_USERS * 64 / 256, 256, 0, stream>>>(rptr, rcols, rv[c], ptr_, N_POIS, utr, su, su, N_USERS);
        spmm_kernel<<<N_POIS * 64 / 256, 256, 0, stream>>>(cptr, crows, cv[c], utr, N_USERS, ptr_, sp, sp, N_POIS);
        // idf (+)= fwn_c * (su @ Wu^T)   (c==0 initializes)
        gemm_aw_kernel<<<N_USERS / 32, 256, 0, stream>>>(su, chs[c].Wu, nullptr, idf, fw3, chs[c].fsel, (c == 0) ? 1 : 0, N_USERS);
        ufsel_kernel<<<BATCH, 128, 0, stream>>>(su, chs[c].Wu, uidx, ufs + (size_t)c * BATCH * DIM);
        // pf = sp @ Wp^T
        gemm_aw_kernel<<<N_POIS / 32, 256, 0, stream>>>(sp, chs[c].Wp, pf, nullptr, fw3, 0, 0, N_POIS);
        predict_kernel<<<BATCH * NPOS * 64 / 256, 256, 0, stream>>>(
            ufs + (size_t)c * BATCH * DIM, pf, pidx, w3, chs[c].wsel, alt);
    }

    loss_kernel<<<1, 256, 0, stream>>>(alt, labels, outp);
    bs_kernel<<<BATCH, 128, 0, stream>>>(idf, Wss, bias, uidx, bst);
    dim3 sg(NCHUNK, 4);
    score_topk_kernel<<<sg, 256, 0, stream>>>(idf, bst, cand_s, cand_i);
    topk_merge_kernel<<<BATCH, 256, 0, stream>>>(cand_s, cand_i, guf, outp);
}

// Round 9
// 1267.111 us; speedup vs baseline: 1.0308x; 1.0308x over previous
//
#include <hip/hip_runtime.h>

#define N_USERS 40000
#define N_POIS  20000
#define DIM     128
#define N_EDGES 500000
#define BATCH   256
#define NPOS    100
#define TOPK    20
#define NCHUNK  128
#define CPT     313   // ceil(40000/128)

__device__ __forceinline__ int iclamp(int x, int lo, int hi) {
    return x < lo ? lo : (x > hi ? hi : x);
}
__device__ __forceinline__ float softmax3(const float* p, int sel) {
    float a0 = p[0], a1 = p[1], a2 = p[2];
    float m = fmaxf(a0, fmaxf(a1, a2));
    float e0 = expf(a0 - m), e1 = expf(a1 - m), e2 = expf(a2 - m);
    float den = e0 + e1 + e2;
    float e = (sel == 0) ? e0 : ((sel == 1) ? e1 : e2);
    return e / den;
}

// ---------------- zero init ----------------
__global__ void zero_kernel(unsigned int* __restrict__ p, int nwords) {
    int i = blockIdx.x * blockDim.x + threadIdx.x;
    if (i < nwords) p[i] = 0u;
}

// ---------------- CSR build ----------------
__global__ void hist_kernel(const int* __restrict__ er, const int* __restrict__ ec,
                            int* __restrict__ rcnt, int* __restrict__ ccnt) {
    int e = blockIdx.x * blockDim.x + threadIdx.x;
    if (e < N_EDGES) {
        atomicAdd(&rcnt[iclamp(er[e], 0, N_USERS - 1)], 1);
        atomicAdd(&ccnt[iclamp(ec[e], 0, N_POIS - 1)], 1);
    }
}

__global__ void scan_kernel(const int* __restrict__ rcnt, int* __restrict__ rptr,
                            const int* __restrict__ ccnt, int* __restrict__ cptr) {
    const int* cnt = blockIdx.x ? ccnt : rcnt;
    int* ptr = blockIdx.x ? cptr : rptr;
    int n = blockIdx.x ? N_POIS : N_USERS;
    __shared__ int part[256];
    __shared__ int pref[257];
    int C = (n + 255) / 256;
    int lo = threadIdx.x * C;
    int hi = lo + C; if (hi > n) hi = n;
    int s = 0;
    for (int i = lo; i < hi; i++) s += cnt[i];
    part[threadIdx.x] = s;
    __syncthreads();
    if (threadIdx.x == 0) {
        int r = 0;
        for (int i = 0; i < 256; i++) { pref[i] = r; r += part[i]; }
        pref[256] = r;
    }
    __syncthreads();
    int r = pref[threadIdx.x];
    for (int i = lo; i < hi; i++) { ptr[i] = r; r += cnt[i]; }
    if (threadIdx.x == 0) ptr[n] = pref[256];
}

__global__ void fill_kernel(const int* __restrict__ er, const int* __restrict__ ec,
                            const int* __restrict__ rptr, const int* __restrict__ cptr,
                            int* __restrict__ rcur, int* __restrict__ ccur,
                            int* __restrict__ rcols, int* __restrict__ crows,
                            const float* __restrict__ ck, const float* __restrict__ fv,
                            const float* __restrict__ cs,
                            float* __restrict__ rv0, float* __restrict__ rv1, float* __restrict__ rv2,
                            float* __restrict__ cv0, float* __restrict__ cv1, float* __restrict__ cv2) {
    int e = blockIdx.x * blockDim.x + threadIdx.x;
    if (e < N_EDGES) {
        int r = iclamp(er[e], 0, N_USERS - 1), c = iclamp(ec[e], 0, N_POIS - 1);
        float v0 = ck[e], v1 = fv[e], v2 = cs[e];
        int pr = iclamp(rptr[r] + atomicAdd(&rcur[r], 1), 0, N_EDGES - 1);
        rcols[pr] = c; rv0[pr] = v0; rv1[pr] = v1; rv2[pr] = v2;
        int pc = iclamp(cptr[c] + atomicAdd(&ccur[c], 1), 0, N_EDGES - 1);
        crows[pc] = r; cv0[pc] = v0; cv1[pc] = v1; cv2[pc] = v2;
    }
}

// ---------------- FUSED 3-channel SpMM: one wave per row; 6 FMA chains ----------------
// raw3/acc3 layout [row][3][DIM]. src row c: src + c*src_rs (+ch*src_cs). base likewise.
template <int SHARED_SRC>
__global__ __launch_bounds__(256) void spmm3_kernel(
        const int* __restrict__ ptr, const int* __restrict__ nbr,
        const float* __restrict__ v0a, const float* __restrict__ v1a, const float* __restrict__ v2a,
        const float* __restrict__ src, int src_rs, int src_cs,
        float* __restrict__ raw3,
        const float* __restrict__ base, int base_rs, int base_cs,
        float* __restrict__ acc3, int nrows) {
    int wid = (blockIdx.x * blockDim.x + threadIdx.x) >> 6;
    int lane = threadIdx.x & 63;
    if (wid >= nrows) return;
    int beg = __builtin_amdgcn_readfirstlane(iclamp(ptr[wid], 0, N_EDGES));
    int end = __builtin_amdgcn_readfirstlane(iclamp(ptr[wid + 1], 0, N_EDGES));
    if (end < beg) end = beg;
    int lo2 = lane * 2;
    float a0x = 0.f, a0y = 0.f, a1x = 0.f, a1y = 0.f, a2x = 0.f, a2y = 0.f;
    int e = beg;
    if (SHARED_SRC) {
        for (; e + 4 <= end; e += 4) {
            int cA = nbr[e], cB = nbr[e + 1], cC = nbr[e + 2], cD = nbr[e + 3];
            float2 pA = *(const float2*)(src + (size_t)cA * src_rs + lo2);
            float2 pB = *(const float2*)(src + (size_t)cB * src_rs + lo2);
            float2 pC = *(const float2*)(src + (size_t)cC * src_rs + lo2);
            float2 pD = *(const float2*)(src + (size_t)cD * src_rs + lo2);
            float vA0 = v0a[e], vB0 = v0a[e + 1], vC0 = v0a[e + 2], vD0 = v0a[e + 3];
            float vA1 = v1a[e], vB1 = v1a[e + 1], vC1 = v1a[e + 2], vD1 = v1a[e + 3];
            float vA2 = v2a[e], vB2 = v2a[e + 1], vC2 = v2a[e + 2], vD2 = v2a[e + 3];
            a0x = fmaf(vA0, pA.x, fmaf(vB0, pB.x, fmaf(vC0, pC.x, fmaf(vD0, pD.x, a0x))));
            a0y = fmaf(vA0, pA.y, fmaf(vB0, pB.y, fmaf(vC0, pC.y, fmaf(vD0, pD.y, a0y))));
            a1x = fmaf(vA1, pA.x, fmaf(vB1, pB.x, fmaf(vC1, pC.x, fmaf(vD1, pD.x, a1x))));
            a1y = fmaf(vA1, pA.y, fmaf(vB1, pB.y, fmaf(vC1, pC.y, fmaf(vD1, pD.y, a1y))));
            a2x = fmaf(vA2, pA.x, fmaf(vB2, pB.x, fmaf(vC2, pC.x, fmaf(vD2, pD.x, a2x))));
            a2y = fmaf(vA2, pA.y, fmaf(vB2, pB.y, fmaf(vC2, pC.y, fmaf(vD2, pD.y, a2y))));
        }
        for (; e < end; e++) {
            int c = nbr[e];
            float2 p = *(const float2*)(src + (size_t)c * src_rs + lo2);
            float v0 = v0a[e], v1 = v1a[e], v2 = v2a[e];
            a0x = fmaf(v0, p.x, a0x); a0y = fmaf(v0, p.y, a0y);
            a1x = fmaf(v1, p.x, a1x); a1y = fmaf(v1, p.y, a1y);
            a2x = fmaf(v2, p.x, a2x); a2y = fmaf(v2, p.y, a2y);
        }
    } else {
        for (; e + 2 <= end; e += 2) {
            int cA = nbr[e], cB = nbr[e + 1];
            const float* rA = src + (size_t)cA * src_rs + lo2;
            const float* rB = src + (size_t)cB * src_rs + lo2;
            float2 pA0 = *(const float2*)(rA);
            float2 pA1 = *(const float2*)(rA + src_cs);
            float2 pA2 = *(const float2*)(rA + 2 * src_cs);
            float2 pB0 = *(const float2*)(rB);
            float2 pB1 = *(const float2*)(rB + src_cs);
            float2 pB2 = *(const float2*)(rB + 2 * src_cs);
            float vA0 = v0a[e], vB0 = v0a[e + 1];
            float vA1 = v1a[e], vB1 = v1a[e + 1];
            float vA2 = v2a[e], vB2 = v2a[e + 1];
            a0x = fmaf(vA0, pA0.x, fmaf(vB0, pB0.x, a0x));
            a0y = fmaf(vA0, pA0.y, fmaf(vB0, pB0.y, a0y));
            a1x = fmaf(vA1, pA1.x, fmaf(vB1, pB1.x, a1x));
            a1y = fmaf(vA1, pA1.y, fmaf(vB1, pB1.y, a1y));
            a2x = fmaf(vA2, pA2.x, fmaf(vB2, pB2.x, a2x));
            a2y = fmaf(vA2, pA2.y, fmaf(vB2, pB2.y, a2y));
        }
        for (; e < end; e++) {
            int c = nbr[e];
            const float* r = src + (size_t)c * src_rs + lo2;
            float2 p0 = *(const float2*)(r);
            float2 p1 = *(const float2*)(r + src_cs);
            float2 p2 = *(const float2*)(r + 2 * src_cs);
            float v0 = v0a[e], v1 = v1a[e], v2 = v2a[e];
            a0x = fmaf(v0, p0.x, a0x); a0y = fmaf(v0, p0.y, a0y);
            a1x = fmaf(v1, p1.x, a1x); a1y = fmaf(v1, p1.y, a1y);
            a2x = fmaf(v2, p2.x, a2x); a2y = fmaf(v2, p2.y, a2y);
        }
    }
    float n0 = a0x * a0x + a0y * a0y;
    float n1 = a1x * a1x + a1y * a1y;
    float n2 = a2x * a2x + a2y * a2y;
    #pragma unroll
    for (int o = 32; o > 0; o >>= 1) {
        n0 += __shfl_xor(n0, o, 64);
        n1 += __shfl_xor(n1, o, 64);
        n2 += __shfl_xor(n2, o, 64);
    }
    float i0 = rsqrtf(fmaxf(n0, 1e-30f));
    float i1 = rsqrtf(fmaxf(n1, 1e-30f));
    float i2 = rsqrtf(fmaxf(n2, 1e-30f));
    size_t ro = (size_t)wid * (3 * DIM) + lo2;
    *(float2*)(raw3 + ro)           = make_float2(a0x, a0y);
    *(float2*)(raw3 + ro + DIM)     = make_float2(a1x, a1y);
    *(float2*)(raw3 + ro + 2 * DIM) = make_float2(a2x, a2y);
    const float* bp = base + (size_t)wid * base_rs + lo2;
    float2 b0 = *(const float2*)(bp);
    float2 b1 = *(const float2*)(bp + base_cs);
    float2 b2 = *(const float2*)(bp + 2 * base_cs);
    *(float2*)(acc3 + ro)           = make_float2(b0.x + a0x * i0, b0.y + a0y * i0);
    *(float2*)(acc3 + ro + DIM)     = make_float2(b1.x + a1x * i1, b1.y + a1y * i1);
    *(float2*)(acc3 + ro + 2 * DIM) = make_float2(b2.x + a2x * i2, b2.y + a2y * i2);
}

// ---------------- single-channel SpMM (fallback path) ----------------
__global__ __launch_bounds__(256) void spmm_kernel(
        const int* __restrict__ ptr, const int* __restrict__ nbr,
        const float* __restrict__ vals,
        const float* __restrict__ src,
        float* __restrict__ raw,
        const float* __restrict__ base,
        float* __restrict__ acc, int nrows) {
    int wid = (blockIdx.x * blockDim.x + threadIdx.x) >> 6;
    int lane = threadIdx.x & 63;
    if (wid >= nrows) return;
    int beg = __builtin_amdgcn_readfirstlane(iclamp(ptr[wid], 0, N_EDGES));
    int end = __builtin_amdgcn_readfirstlane(iclamp(ptr[wid + 1], 0, N_EDGES));
    if (end < beg) end = beg;
    float ax = 0.f, ay = 0.f;
    int e = beg;
    int lo2 = lane * 2;
    for (; e + 8 <= end; e += 8) {
        int c0 = nbr[e + 0], c1 = nbr[e + 1], c2 = nbr[e + 2], c3 = nbr[e + 3];
        int c4 = nbr[e + 4], c5 = nbr[e + 5], c6 = nbr[e + 6], c7 = nbr[e + 7];
        float v0 = vals[e + 0], v1 = vals[e + 1], v2 = vals[e + 2], v3 = vals[e + 3];
        float v4 = vals[e + 4], v5 = vals[e + 5], v6 = vals[e + 6], v7 = vals[e + 7];
        float2 p0 = *(const float2*)(src + (size_t)c0 * DIM + lo2);
        float2 p1 = *(const float2*)(src + (size_t)c1 * DIM + lo2);
        float2 p2 = *(const float2*)(src + (size_t)c2 * DIM + lo2);
        float2 p3 = *(const float2*)(src + (size_t)c3 * DIM + lo2);
        float2 p4 = *(const float2*)(src + (size_t)c4 * DIM + lo2);
        float2 p5 = *(const float2*)(src + (size_t)c5 * DIM + lo2);
        float2 p6 = *(const float2*)(src + (size_t)c6 * DIM + lo2);
        float2 p7 = *(const float2*)(src + (size_t)c7 * DIM + lo2);
        ax = fmaf(v0, p0.x, fmaf(v1, p1.x, fmaf(v2, p2.x, fmaf(v3, p3.x, ax))));
        ax = fmaf(v4, p4.x, fmaf(v5, p5.x, fmaf(v6, p6.x, fmaf(v7, p7.x, ax))));
        ay = fmaf(v0, p0.y, fmaf(v1, p1.y, fmaf(v2, p2.y, fmaf(v3, p3.y, ay))));
        ay = fmaf(v4, p4.y, fmaf(v5, p5.y, fmaf(v6, p6.y, fmaf(v7, p7.y, ay))));
    }
    for (; e < end; e++) {
        int c = nbr[e];
        float v = vals[e];
        float2 pv = *(const float2*)(src + (size_t)c * DIM + lo2);
        ax = fmaf(v, pv.x, ax);
        ay = fmaf(v, pv.y, ay);
    }
    float n2 = ax * ax + ay * ay;
    #pragma unroll
    for (int o = 32; o > 0; o >>= 1) n2 += __shfl_xor(n2, o, 64);
    float inv = rsqrtf(fmaxf(n2, 1e-30f));
    *(float2*)(raw + (size_t)wid * DIM + lo2) = make_float2(ax, ay);
    float2 bv = *(const float2*)(base + (size_t)wid * DIM + lo2);
    *(float2*)(acc + (size_t)wid * DIM + lo2) =
        make_float2(bv.x + ax * inv, bv.y + ay * inv);
}

// ---------------- out = A[Mx128] @ W^T ; strided A rows; A-tile in LDS ----------------
__global__ __launch_bounds__(256) void gemm_aw_kernel(
        const float* __restrict__ A, int ars,
        const float* __restrict__ W,
        float* __restrict__ store, float* __restrict__ accum,
        const float* __restrict__ fw3, int fsel, int first, int M) {
    __shared__ float Al[32 * 128];                 // 16 KB
    int i0 = blockIdx.x * 32;
    float4* Al4 = (float4*)Al;
    for (int qi = threadIdx.x; qi < 1024; qi += 256) {
        int r = qi >> 5, q = qi & 31;
        Al4[qi] = *(const float4*)(A + (size_t)(i0 + r) * ars + q * 4);
    }
    __syncthreads();
    float coef = accum ? softmax3(fw3, fsel) : 0.f;
    int j2 = threadIdx.x & 63;                     // cols j2 and j2+64
    int rg = threadIdx.x >> 6;                     // rows rg + 4*m, m=0..7
    const float4* W0 = (const float4*)(W + (size_t)j2 * DIM);
    const float4* W1 = (const float4*)(W + (size_t)(j2 + 64) * DIM);
    float acc0[8], acc1[8];
    #pragma unroll
    for (int m = 0; m < 8; m++) { acc0[m] = 0.f; acc1[m] = 0.f; }
    for (int kq = 0; kq < 32; kq++) {
        float4 w0 = W0[kq];
        float4 w1 = W1[kq];
        #pragma unroll
        for (int m = 0; m < 8; m++) {
            float4 a = Al4[(rg + 4 * m) * 32 + kq];
            acc0[m] = fmaf(a.x, w0.x, acc0[m]); acc0[m] = fmaf(a.y, w0.y, acc0[m]);
            acc0[m] = fmaf(a.z, w0.z, acc0[m]); acc0[m] = fmaf(a.w, w0.w, acc0[m]);
            acc1[m] = fmaf(a.x, w1.x, acc1[m]); acc1[m] = fmaf(a.y, w1.y, acc1[m]);
            acc1[m] = fmaf(a.z, w1.z, acc1[m]); acc1[m] = fmaf(a.w, w1.w, acc1[m]);
        }
    }
    #pragma unroll
    for (int m = 0; m < 8; m++) {
        int i = i0 + rg + 4 * m;
        if (i >= M) continue;
        size_t o0 = (size_t)i * DIM + j2;
        size_t o1 = o0 + 64;
        if (store) { store[o0] = acc0[m]; store[o1] = acc1[m]; }
        if (accum) {
            float p0 = first ? 0.f : accum[o0];
            float p1 = first ? 0.f : accum[o1];
            accum[o0] = p0 + coef * acc0[m];
            accum[o1] = p1 + coef * acc1[m];
        }
    }
}

// ---------------- 256 selected rows of uf = su @ Wu^T (strided A) ----------------
__global__ void ufsel_kernel(const float* __restrict__ su, int ars,
                             const float* __restrict__ W,
                             const int* __restrict__ uidx, float* __restrict__ outsel) {
    int b = blockIdx.x, j = threadIdx.x;  // block 128
    __shared__ float ar[128];
    int u = iclamp(uidx[b], 0, N_USERS - 1);
    ar[j] = su[(size_t)u * ars + j];
    __syncthreads();
    const float4* Wr = (const float4*)(W + (size_t)j * DIM);
    float acc = 0.f;
    #pragma unroll 8
    for (int q = 0; q < 32; q++) {
        float4 wq = Wr[q];
        acc = fmaf(ar[4 * q + 0], wq.x, acc);
        acc = fmaf(ar[4 * q + 1], wq.y, acc);
        acc = fmaf(ar[4 * q + 2], wq.z, acc);
        acc = fmaf(ar[4 * q + 3], wq.w, acc);
    }
    outsel[(size_t)b * DIM + j] = acc;
}

// ---------------- alt[b,j] += wn_c * dot(uf_c[b], pf_c[poi]) ----------------
__global__ __launch_bounds__(256) void predict_kernel(
        const float* __restrict__ ufs, const float* __restrict__ pf,
        const int* __restrict__ pidx, const float* __restrict__ w3,
        int wsel, float* __restrict__ alt) {
    int wid = (blockIdx.x * blockDim.x + threadIdx.x) >> 6;
    int lane = threadIdx.x & 63;
    if (wid >= BATCH * NPOS) return;
    int b = wid / NPOS;
    int poi = iclamp(pidx[wid], 0, N_POIS - 1);
    const float2 uv = *(const float2*)(ufs + (size_t)b * DIM + lane * 2);
    const float2 pv = *(const float2*)(pf + (size_t)poi * DIM + lane * 2);
    float s = uv.x * pv.x + uv.y * pv.y;
    #pragma unroll
    for (int o = 32; o > 0; o >>= 1) s += __shfl_xor(s, o, 64);
    if (lane == 0) {
        float coef = softmax3(w3, wsel);
        alt[wid] += coef * s;
    }
}

// ---------------- BCE loss ----------------
__global__ void loss_kernel(const float* __restrict__ alt, const float* __restrict__ labels,
                            float* __restrict__ out) {
    __shared__ float red[256];
    float s = 0.f;
    for (int i = threadIdx.x; i < BATCH * NPOS; i += 256) {
        float x = alt[i], y = labels[i];
        s += fmaxf(x, 0.f) - x * y + log1pf(expf(-fabsf(x)));
    }
    red[threadIdx.x] = s;
    __syncthreads();
    for (int off = 128; off > 0; off >>= 1) {
        if (threadIdx.x < off) red[threadIdx.x] += red[threadIdx.x + off];
        __syncthreads();
    }
    if (threadIdx.x == 0) out[0] = red[0] / (float)(BATCH * NPOS);
}

// ---------------- bst[j][b] = id_feat[cur[b]] @ Ws^T + bias (transposed) ----------------
__global__ void bs_kernel(const float* __restrict__ idf, const float* __restrict__ Ws,
                          const float* __restrict__ bias, const int* __restrict__ uidx,
                          float* __restrict__ bst) {
    int b = blockIdx.x, j = threadIdx.x;  // block 128
    __shared__ float ar[128];
    int u = iclamp(uidx[b], 0, N_USERS - 1);
    ar[j] = idf[(size_t)u * DIM + j];
    __syncthreads();
    const float4* Wr = (const float4*)(Ws + (size_t)j * DIM);
    float acc = 0.f;
    #pragma unroll 8
    for (int q = 0; q < 32; q++) {
        float4 wq = Wr[q];
        acc = fmaf(ar[4 * q + 0], wq.x, acc);
        acc = fmaf(ar[4 * q + 1], wq.y, acc);
        acc = fmaf(ar[4 * q + 2], wq.z, acc);
        acc = fmaf(ar[4 * q + 3], wq.w, acc);
    }
    bst[(size_t)j * BATCH + b] = acc + bias[j];
}

__device__ __forceinline__ void topk_insert(float s, int u, float* ts, int* ti) {
    if (s > ts[TOPK - 1]) {
        #pragma unroll
        for (int j = TOPK - 1; j > 0; --j) {
            bool above = s > ts[j - 1];
            bool here = (!above) && (s > ts[j]);
            float nv = above ? ts[j - 1] : (here ? s : ts[j]);
            int ni = above ? ti[j - 1] : (here ? u : ti[j]);
            ts[j] = nv; ti[j] = ni;
        }
        if (s > ts[0]) { ts[0] = s; ti[0] = u; }
    }
}

// ---------------- fused uu scores + per-block top-20: 32 KB LDS (5 blocks/CU) ----------------
__global__ __launch_bounds__(256) void score_topk_kernel(
        const float* __restrict__ idf, const float* __restrict__ bst,
        float* __restrict__ cand_s, int* __restrict__ cand_i) {
    __shared__ __align__(16) unsigned char smraw[32768];
    float* bsl = (float*)smraw;                         // phase 1: [q][b][4] 32 KB
    float* ms  = (float*)smraw;                         // phase 2: [k][tid] floats 20 KB
    unsigned short* mi = (unsigned short*)(smraw + 20480);  // phase 2: [k][tid] u16 10 KB
    int cid = blockIdx.x, bg = blockIdx.y;
    for (int idx = threadIdx.x; idx < 32 * 64; idx += 256) {
        int b = idx & 63, q = idx >> 6;
        float4 v;
        v.x = bst[(size_t)(4 * q + 0) * BATCH + bg * 64 + b];
        v.y = bst[(size_t)(4 * q + 1) * BATCH + bg * 64 + b];
        v.z = bst[(size_t)(4 * q + 2) * BATCH + bg * 64 + b];
        v.w = bst[(size_t)(4 * q + 3) * BATCH + bg * 64 + b];
        *(float4*)&bsl[(size_t)idx * 4] = v;
    }
    __syncthreads();
    int b_l = threadIdx.x & 63, us = threadIdx.x >> 6;
    const float4* bcol = (const float4*)&bsl[b_l * 4];  // stride 64 float4s between q
    float ts[TOPK]; int ti[TOPK];
    #pragma unroll
    for (int k = 0; k < TOPK; k++) { ts[k] = -3.0e38f; ti[k] = 0; }
    int lo = cid * CPT;
    int hi = lo + CPT; if (hi > N_USERS) hi = N_USERS;
    for (int u0 = lo + us * 4; u0 < hi; u0 += 16) {
        int uc1 = u0 + 1 < N_USERS ? u0 + 1 : N_USERS - 1;
        int uc2 = u0 + 2 < N_USERS ? u0 + 2 : N_USERS - 1;
        int uc3 = u0 + 3 < N_USERS ? u0 + 3 : N_USERS - 1;
        const float4* r0 = (const float4*)(idf + (size_t)u0 * DIM);
        const float4* r1 = (const float4*)(idf + (size_t)uc1 * DIM);
        const float4* r2 = (const float4*)(idf + (size_t)uc2 * DIM);
        const float4* r3 = (const float4*)(idf + (size_t)uc3 * DIM);
        float s0 = 0.f, s1 = 0.f, s2 = 0.f, s3 = 0.f;
        #pragma unroll 8
        for (int q = 0; q < 32; q++) {
            float4 bb = bcol[q * 64];
            float4 a0 = r0[q], a1 = r1[q], a2 = r2[q], a3 = r3[q];
            s0 = fmaf(a0.x, bb.x, fmaf(a0.y, bb.y, fmaf(a0.z, bb.z, fmaf(a0.w, bb.w, s0))));
            s1 = fmaf(a1.x, bb.x, fmaf(a1.y, bb.y, fmaf(a1.z, bb.z, fmaf(a1.w, bb.w, s1))));
            s2 = fmaf(a2.x, bb.x, fmaf(a2.y, bb.y, fmaf(a2.z, bb.z, fmaf(a2.w, bb.w, s2))));
            s3 = fmaf(a3.x, bb.x, fmaf(a3.y, bb.y, fmaf(a3.z, bb.z, fmaf(a3.w, bb.w, s3))));
        }
        topk_insert(s0, u0, ts, ti);
        if (u0 + 1 < hi) topk_insert(s1, u0 + 1, ts, ti);
        if (u0 + 2 < hi) topk_insert(s2, u0 + 2, ts, ti);
        if (u0 + 3 < hi) topk_insert(s3, u0 + 3, ts, ti);
    }
    __syncthreads();
    #pragma unroll
    for (int k = 0; k < TOPK; k++) {
        ms[k * 256 + threadIdx.x] = ts[k];
        mi[k * 256 + threadIdx.x] = (unsigned short)ti[k];
    }
    __syncthreads();
    if (threadIdx.x < 64) {
        int t = threadIdx.x;
        int p0 = 0, p1 = 0, p2 = 0, p3 = 0;
        size_t ob = (((size_t)cid) * 256 + bg * 64 + t) * TOPK;
        for (int k = 0; k < TOPK; k++) {
            float h0 = ms[p0 * 256 + 0 * 64 + t];
            float h1 = ms[p1 * 256 + 1 * 64 + t];
            float h2 = ms[p2 * 256 + 2 * 64 + t];
            float h3 = ms[p3 * 256 + 3 * 64 + t];
            float best = h0; int which = 0;
            if (h1 > best) { best = h1; which = 1; }
            if (h2 > best) { best = h2; which = 2; }
            if (h3 > best) { best = h3; which = 3; }
            int idx;
            if (which == 0)      { idx = mi[p0 * 256 + 0 * 64 + t]; p0++; }
            else if (which == 1) { idx = mi[p1 * 256 + 1 * 64 + t]; p1++; }
            else if (which == 2) { idx = mi[p2 * 256 + 2 * 64 + t]; p2++; }
            else                 { idx = mi[p3 * 256 + 3 * 64 + t]; p3++; }
            cand_s[ob + k] = best;
            cand_i[ob + k] = idx;
        }
    }
}

// ---------------- global merge + softmax + weighted gather ----------------
__global__ void topk_merge_kernel(const float* __restrict__ cand_s, const int* __restrict__ cand_i,
                                  const float* __restrict__ guf,
                                  float* __restrict__ outp) {
    int b = blockIdx.x, t = threadIdx.x;  // block 128 (= NCHUNK)
    __shared__ float rs[128]; __shared__ int ru[128]; __shared__ int rt[128];
    __shared__ float win_s[TOPK]; __shared__ int win_u[TOPK]; __shared__ float wk[TOPK];
    __shared__ int winner;
    int ptr = 0;
    size_t base = ((size_t)t * 256 + b) * TOPK;
    for (int k = 0; k < TOPK; k++) {
        rs[t] = (ptr < TOPK) ? cand_s[base + ptr] : -3.0e38f;
        ru[t] = (ptr < TOPK) ? cand_i[base + ptr] : 0;
        rt[t] = t;
        __syncthreads();
        for (int off = 64; off > 0; off >>= 1) {
            if (t < off && rs[t + off] > rs[t]) {
                rs[t] = rs[t + off]; ru[t] = ru[t + off]; rt[t] = rt[t + off];
            }
            __syncthreads();
        }
        if (t == 0) { win_s[k] = rs[0]; win_u[k] = iclamp(ru[0], 0, N_USERS - 1); winner = rt[0]; }
        __syncthreads();
        if (t == winner) ptr++;
        __syncthreads();
    }
    if (t == 0) {
        float m = win_s[0], den = 0.f;
        for (int k = 0; k < TOPK; k++) { wk[k] = expf(win_s[k] - m); den += wk[k]; }
        float inv = 1.f / den;
        for (int k = 0; k < TOPK; k++) wk[k] *= inv;
    }
    __syncthreads();
    float acc = 0.f;
    #pragma unroll
    for (int k = 0; k < TOPK; k++)
        acc = fmaf(wk[k], guf[(size_t)win_u[k] * DIM + t], acc);
    outp[1 + (size_t)b * DIM + t] = acc;
}

extern "C" void kernel_launch(void* const* d_in, const int* in_sizes, int n_in,
                              void* d_out, int out_size, void* d_ws, size_t ws_size,
                              hipStream_t stream) {
    (void)in_sizes; (void)n_in; (void)out_size;
    const int*   er      = (const int*)d_in[0];
    const int*   ec      = (const int*)d_in[1];
    const float* click   = (const float*)d_in[2];
    const float* favor   = (const float*)d_in[3];
    const float* consume = (const float*)d_in[4];
    const float* uid     = (const float*)d_in[5];
    const float* pid     = (const float*)d_in[6];
    const int*   uidx    = (const int*)d_in[7];
    const int*   pidx    = (const int*)d_in[8];
    const float* labels  = (const float*)d_in[9];
    const float* guf     = (const float*)d_in[10];
    const float* w3      = (const float*)d_in[11];
    const float* fw3     = (const float*)d_in[12];
    const float* Wuc     = (const float*)d_in[13];
    const float* Wpc     = (const float*)d_in[14];
    const float* Wufv    = (const float*)d_in[15];
    const float* Wpfv    = (const float*)d_in[16];
    const float* Wuco    = (const float*)d_in[17];
    const float* Wpco    = (const float*)d_in[18];
    const float* Wss     = (const float*)d_in[19];
    const float* bias    = (const float*)d_in[20];
    float* outp = (float*)d_out;

    char* ws = (char*)d_ws;
    size_t off = 0;
    auto carve = [&](size_t bytes) -> void* {
        off = (off + 255) & ~(size_t)255;
        void* p = ws + off;
        off += bytes;
        return p;
    };
    // common small buffers + CSR
    float* ufs = (float*)carve(4ll * 3 * BATCH * DIM);
    float* alt = (float*)carve(4ll * BATCH * NPOS);
    float* bst = (float*)carve(4ll * DIM * BATCH);
    int* rptr = (int*)carve(4 * (N_USERS + 1));
    int* cptr = (int*)carve(4 * (N_POIS + 1));
    int* cnts = (int*)carve(4 * (2 * (N_USERS + N_POIS)));
    int* rcnt = cnts;
    int* ccnt = cnts + N_USERS;
    int* rcur = ccnt + N_POIS;
    int* ccur = rcur + N_USERS;
    int* rcols = (int*)carve(4 * (size_t)N_EDGES);
    int* crows = (int*)carve(4 * (size_t)N_EDGES);
    float* rv[3]; float* cv[3];
    for (int c = 0; c < 3; c++) rv[c] = (float*)carve(4 * (size_t)N_EDGES);
    for (int c = 0; c < 3; c++) cv[c] = (float*)carve(4 * (size_t)N_EDGES);

    const size_t smalls = off;
    // fused path needs: utr3 + su3 (61.44M each) + sp3 + ptr3 (30.72M each) [idf aliases ptr3]
    const size_t fused_need = smalls + (4ll * N_USERS * 3 * DIM) * 2 + (4ll * N_POIS * 3 * DIM) * 2 + (1 << 20);
    bool fused = ws_size >= fused_need;

    zero_kernel<<<(2 * (N_USERS + N_POIS) + 255) / 256, 256, 0, stream>>>((unsigned int*)cnts, 2 * (N_USERS + N_POIS));
    zero_kernel<<<(BATCH * NPOS + 255) / 256, 256, 0, stream>>>((unsigned int*)alt, BATCH * NPOS);
    hist_kernel<<<(N_EDGES + 255) / 256, 256, 0, stream>>>(er, ec, rcnt, ccnt);
    scan_kernel<<<2, 256, 0, stream>>>(rcnt, rptr, ccnt, cptr);
    fill_kernel<<<(N_EDGES + 255) / 256, 256, 0, stream>>>(
        er, ec, rptr, cptr, rcur, ccur, rcols, crows,
        click, favor, consume, rv[0], rv[1], rv[2], cv[0], cv[1], cv[2]);

    struct Ch { const float* Wu; const float* Wp; int wsel; int fsel; };
    // wn (softmax over w[1,3]):  favor=0, click=1, consume=2
    // fwn (softmax over fw[3,1]): favor=0, consume=1, click=2
    Ch chs[3] = { { Wuc,  Wpc,  1, 2 },     // ch0 = click
                  { Wufv, Wpfv, 0, 0 },     // ch1 = favor
                  { Wuco, Wpco, 2, 1 } };   // ch2 = consume

    float* idf; float* cand_s; int* cand_i;

    if (fused) {
        float* utr3 = (float*)carve(4ll * N_USERS * 3 * DIM);   // raw u ; pf alias later
        float* ptr3 = (float*)carve(4ll * N_POIS * 3 * DIM);    // raw p ; idf alias later
        float* su3  = (float*)carve(4ll * N_USERS * 3 * DIM);   // cand alias later
        float* sp3  = (float*)carve(4ll * N_POIS * 3 * DIM);
        idf = ptr3;            // ptr3 dead after L2 poi hop; idf written after
        float* pf = utr3;      // utr3 dead after L2 poi hop
        cand_s = su3;          // su3 dead before score_topk
        cand_i = (int*)(su3 + (size_t)NCHUNK * BATCH * TOPK);

        // GCN: 4 fused dispatches
        spmm3_kernel<1><<<N_USERS * 64 / 256, 256, 0, stream>>>(
            rptr, rcols, rv[0], rv[1], rv[2], pid, DIM, 0, utr3, uid, DIM, 0, su3, N_USERS);
        spmm3_kernel<0><<<N_POIS * 64 / 256, 256, 0, stream>>>(
            cptr, crows, cv[0], cv[1], cv[2], utr3, 3 * DIM, DIM, ptr3, pid, DIM, 0, sp3, N_POIS);
        spmm3_kernel<0><<<N_USERS * 64 / 256, 256, 0, stream>>>(
            rptr, rcols, rv[0], rv[1], rv[2], ptr3, 3 * DIM, DIM, utr3, su3, 3 * DIM, DIM, su3, N_USERS);
        spmm3_kernel<0><<<N_POIS * 64 / 256, 256, 0, stream>>>(
            cptr, crows, cv[0], cv[1], cv[2], utr3, 3 * DIM, DIM, ptr3, sp3, 3 * DIM, DIM, sp3, N_POIS);

        for (int c = 0; c < 3; c++) {
            gemm_aw_kernel<<<N_USERS / 32, 256, 0, stream>>>(
                su3 + c * DIM, 3 * DIM, chs[c].Wu, nullptr, idf, fw3, chs[c].fsel, (c == 0) ? 1 : 0, N_USERS);
            ufsel_kernel<<<BATCH, 128, 0, stream>>>(su3 + c * DIM, 3 * DIM, chs[c].Wu, uidx,
                                                    ufs + (size_t)c * BATCH * DIM);
            gemm_aw_kernel<<<N_POIS / 32, 256, 0, stream>>>(
                sp3 + c * DIM, 3 * DIM, chs[c].Wp, pf + (size_t)c * N_POIS * DIM, nullptr, fw3, 0, 0, N_POIS);
            predict_kernel<<<BATCH * NPOS * 64 / 256, 256, 0, stream>>>(
                ufs + (size_t)c * BATCH * DIM, pf + (size_t)c * N_POIS * DIM, pidx, w3, chs[c].wsel, alt);
        }
    } else {
        float* utr  = (float*)carve(4ll * N_USERS * DIM);   // raw u ; pf alias
        float* ptr_ = (float*)carve(4ll * N_POIS * DIM);    // raw p
        float* su   = (float*)carve(4ll * N_USERS * DIM);   // cand alias
        float* sp   = (float*)carve(4ll * N_POIS * DIM);
        idf = (float*)carve(4ll * N_USERS * DIM);
        float* pf = utr;
        cand_s = su;
        cand_i = (int*)(su + (size_t)NCHUNK * BATCH * TOPK);

        for (int c = 0; c < 3; c++) {
            spmm_kernel<<<N_USERS * 64 / 256, 256, 0, stream>>>(rptr, rcols, rv[c], pid, utr, uid, su, N_USERS);
            spmm_kernel<<<N_POIS * 64 / 256, 256, 0, stream>>>(cptr, crows, cv[c], utr, ptr_, pid, sp, N_POIS);
            spmm_kernel<<<N_USERS * 64 / 256, 256, 0, stream>>>(rptr, rcols, rv[c], ptr_, utr, su, su, N_USERS);
            spmm_kernel<<<N_POIS * 64 / 256, 256, 0, stream>>>(cptr, crows, cv[c], utr, ptr_, sp, sp, N_POIS);
            gemm_aw_kernel<<<N_USERS / 32, 256, 0, stream>>>(
                su, DIM, chs[c].Wu, nullptr, idf, fw3, chs[c].fsel, (c == 0) ? 1 : 0, N_USERS);
            ufsel_kernel<<<BATCH, 128, 0, stream>>>(su, DIM, chs[c].Wu, uidx, ufs + (size_t)c * BATCH * DIM);
            gemm_aw_kernel<<<N_POIS / 32, 256, 0, stream>>>(
                sp, DIM, chs[c].Wp, pf, nullptr, fw3, 0, 0, N_POIS);
            predict_kernel<<<BATCH * NPOS * 64 / 256, 256, 0, stream>>>(
                ufs + (size_t)c * BATCH * DIM, pf, pidx, w3, chs[c].wsel, alt);
        }
    }

    loss_kernel<<<1, 256, 0, stream>>>(alt, labels, outp);
    bs_kernel<<<BATCH, 128, 0, stream>>>(idf, Wss, bias, uidx, bst);
    dim3 sg(NCHUNK, 4);
    score_topk_kernel<<<sg, 256, 0, stream>>>(idf, bst, cand_s, cand_i);
    topk_merge_kernel<<<BATCH, 128, 0, stream>>>(cand_s, cand_i, guf, outp);
}

// Round 10
// 1149.977 us; speedup vs baseline: 1.1358x; 1.1019x over previous
//
#include <hip/hip_runtime.h>

#define N_USERS 40000
#define N_POIS  20000
#define DIM     128
#define N_EDGES 500000
#define BATCH   256
#define NPOS    100
#define TOPK    20
#define NCHUNK  256
#define CPT     157   // ceil(40000/256)

__device__ __forceinline__ int iclamp(int x, int lo, int hi) {
    return x < lo ? lo : (x > hi ? hi : x);
}
__device__ __forceinline__ float bf2f(unsigned int h) {
    union { unsigned int u; float f; } v; v.u = h << 16; return v.f;
}
__device__ __forceinline__ unsigned short f2bf(float f) {
    union { unsigned int u; float f; } v; v.f = f;
    unsigned int r = v.u + 0x7fffu + ((v.u >> 16) & 1u);
    return (unsigned short)(r >> 16);
}
__device__ __forceinline__ float softmax3(const float* p, int sel) {
    float a0 = p[0], a1 = p[1], a2 = p[2];
    float m = fmaxf(a0, fmaxf(a1, a2));
    float e0 = expf(a0 - m), e1 = expf(a1 - m), e2 = expf(a2 - m);
    float den = e0 + e1 + e2;
    float e = (sel == 0) ? e0 : ((sel == 1) ? e1 : e2);
    return e / den;
}

// ---------------- zero init ----------------
__global__ void zero_kernel(unsigned int* __restrict__ p, int nwords) {
    int i = blockIdx.x * blockDim.x + threadIdx.x;
    if (i < nwords) p[i] = 0u;
}

// ---------------- fp32 -> bf16 cast ----------------
__global__ void cast_bf16_kernel(const float* __restrict__ src, unsigned short* __restrict__ dst,
                                 int n) {
    int i = blockIdx.x * blockDim.x + threadIdx.x;
    if (i < n) {
        float2 v = *(const float2*)(src + 2 * (size_t)i);
        unsigned int o = ((unsigned int)f2bf(v.y) << 16) | (unsigned int)f2bf(v.x);
        *(unsigned int*)(dst + 2 * (size_t)i) = o;
    }
}

// ---------------- CSR build ----------------
__global__ void hist_kernel(const int* __restrict__ er, const int* __restrict__ ec,
                            int* __restrict__ rcnt, int* __restrict__ ccnt) {
    int e = blockIdx.x * blockDim.x + threadIdx.x;
    if (e < N_EDGES) {
        atomicAdd(&rcnt[iclamp(er[e], 0, N_USERS - 1)], 1);
        atomicAdd(&ccnt[iclamp(ec[e], 0, N_POIS - 1)], 1);
    }
}

__global__ void scan_kernel(const int* __restrict__ rcnt, int* __restrict__ rptr,
                            const int* __restrict__ ccnt, int* __restrict__ cptr) {
    const int* cnt = blockIdx.x ? ccnt : rcnt;
    int* ptr = blockIdx.x ? cptr : rptr;
    int n = blockIdx.x ? N_POIS : N_USERS;
    __shared__ int part[256];
    __shared__ int pref[257];
    int C = (n + 255) / 256;
    int lo = threadIdx.x * C;
    int hi = lo + C; if (hi > n) hi = n;
    int s = 0;
    for (int i = lo; i < hi; i++) s += cnt[i];
    part[threadIdx.x] = s;
    __syncthreads();
    if (threadIdx.x == 0) {
        int r = 0;
        for (int i = 0; i < 256; i++) { pref[i] = r; r += part[i]; }
        pref[256] = r;
    }
    __syncthreads();
    int r = pref[threadIdx.x];
    for (int i = lo; i < hi; i++) { ptr[i] = r; r += cnt[i]; }
    if (threadIdx.x == 0) ptr[n] = pref[256];
}

__global__ void fill_kernel(const int* __restrict__ er, const int* __restrict__ ec,
                            const int* __restrict__ rptr, const int* __restrict__ cptr,
                            int* __restrict__ rcur, int* __restrict__ ccur,
                            int* __restrict__ rcols, int* __restrict__ crows,
                            const float* __restrict__ ck, const float* __restrict__ fv,
                            const float* __restrict__ cs,
                            float* __restrict__ rv0, float* __restrict__ rv1, float* __restrict__ rv2,
                            float* __restrict__ cv0, float* __restrict__ cv1, float* __restrict__ cv2) {
    int e = blockIdx.x * blockDim.x + threadIdx.x;
    if (e < N_EDGES) {
        int r = iclamp(er[e], 0, N_USERS - 1), c = iclamp(ec[e], 0, N_POIS - 1);
        float v0 = ck[e], v1 = fv[e], v2 = cs[e];
        int pr = iclamp(rptr[r] + atomicAdd(&rcur[r], 1), 0, N_EDGES - 1);
        rcols[pr] = c; rv0[pr] = v0; rv1[pr] = v1; rv2[pr] = v2;
        int pc = iclamp(cptr[c] + atomicAdd(&ccur[c], 1), 0, N_EDGES - 1);
        crows[pc] = r; cv0[pc] = v0; cv1[pc] = v1; cv2[pc] = v2;
    }
}

// ---------------- SpMM: one wave per row; bf16 src gather; fp32 accum; unroll x8 ----------------
// raw_b (bf16) = A*src ; acc (fp32) = base + raw/||raw||
__global__ __launch_bounds__(256) void spmm_kernel(
        const int* __restrict__ ptr, const int* __restrict__ nbr,
        const float* __restrict__ vals,                 // CSR-ordered
        const unsigned short* __restrict__ src,         // bf16 [*,128]
        unsigned short* __restrict__ raw_b,             // bf16 out
        const float* __restrict__ base,                 // fp32 (may alias acc)
        float* __restrict__ acc, int nrows) {
    int wid = (blockIdx.x * blockDim.x + threadIdx.x) >> 6;
    int lane = threadIdx.x & 63;
    if (wid >= nrows) return;
    int beg = __builtin_amdgcn_readfirstlane(iclamp(ptr[wid], 0, N_EDGES));
    int end = __builtin_amdgcn_readfirstlane(iclamp(ptr[wid + 1], 0, N_EDGES));
    if (end < beg) end = beg;
    float ax = 0.f, ay = 0.f;
    int e = beg;
    int lo2 = lane * 2;
    for (; e + 8 <= end; e += 8) {
        int c0 = nbr[e + 0], c1 = nbr[e + 1], c2 = nbr[e + 2], c3 = nbr[e + 3];
        int c4 = nbr[e + 4], c5 = nbr[e + 5], c6 = nbr[e + 6], c7 = nbr[e + 7];
        float v0 = vals[e + 0], v1 = vals[e + 1], v2 = vals[e + 2], v3 = vals[e + 3];
        float v4 = vals[e + 4], v5 = vals[e + 5], v6 = vals[e + 6], v7 = vals[e + 7];
        unsigned int p0 = *(const unsigned int*)(src + (size_t)c0 * DIM + lo2);
        unsigned int p1 = *(const unsigned int*)(src + (size_t)c1 * DIM + lo2);
        unsigned int p2 = *(const unsigned int*)(src + (size_t)c2 * DIM + lo2);
        unsigned int p3 = *(const unsigned int*)(src + (size_t)c3 * DIM + lo2);
        unsigned int p4 = *(const unsigned int*)(src + (size_t)c4 * DIM + lo2);
        unsigned int p5 = *(const unsigned int*)(src + (size_t)c5 * DIM + lo2);
        unsigned int p6 = *(const unsigned int*)(src + (size_t)c6 * DIM + lo2);
        unsigned int p7 = *(const unsigned int*)(src + (size_t)c7 * DIM + lo2);
        ax = fmaf(v0, bf2f(p0 & 0xffffu), fmaf(v1, bf2f(p1 & 0xffffu),
             fmaf(v2, bf2f(p2 & 0xffffu), fmaf(v3, bf2f(p3 & 0xffffu), ax))));
        ax = fmaf(v4, bf2f(p4 & 0xffffu), fmaf(v5, bf2f(p5 & 0xffffu),
             fmaf(v6, bf2f(p6 & 0xffffu), fmaf(v7, bf2f(p7 & 0xffffu), ax))));
        ay = fmaf(v0, bf2f(p0 >> 16), fmaf(v1, bf2f(p1 >> 16),
             fmaf(v2, bf2f(p2 >> 16), fmaf(v3, bf2f(p3 >> 16), ay))));
        ay = fmaf(v4, bf2f(p4 >> 16), fmaf(v5, bf2f(p5 >> 16),
             fmaf(v6, bf2f(p6 >> 16), fmaf(v7, bf2f(p7 >> 16), ay))));
    }
    for (; e < end; e++) {
        int c = nbr[e];
        float v = vals[e];
        unsigned int pv = *(const unsigned int*)(src + (size_t)c * DIM + lo2);
        ax = fmaf(v, bf2f(pv & 0xffffu), ax);
        ay = fmaf(v, bf2f(pv >> 16), ay);
    }
    float n2 = ax * ax + ay * ay;
    #pragma unroll
    for (int o = 32; o > 0; o >>= 1) n2 += __shfl_xor(n2, o, 64);
    float inv = rsqrtf(fmaxf(n2, 1e-30f));
    *(unsigned int*)(raw_b + (size_t)wid * DIM + lo2) =
        ((unsigned int)f2bf(ay) << 16) | (unsigned int)f2bf(ax);
    float2 bv = *(const float2*)(base + (size_t)wid * DIM + lo2);
    *(float2*)(acc + (size_t)wid * DIM + lo2) =
        make_float2(bv.x + ax * inv, bv.y + ay * inv);
}

// ---------------- out = A[Mx128] @ W^T ; A-tile in LDS ----------------
__global__ __launch_bounds__(256) void gemm_aw_kernel(
        const float* __restrict__ A, const float* __restrict__ W,
        float* __restrict__ store, float* __restrict__ accum,
        const float* __restrict__ fw3, int fsel, int first, int M) {
    __shared__ float Al[32 * 128];                 // 16 KB
    int i0 = blockIdx.x * 32;
    const float4* Ag = (const float4*)(A + (size_t)i0 * DIM);
    float4* Al4 = (float4*)Al;
    for (int qi = threadIdx.x; qi < 1024; qi += 256) Al4[qi] = Ag[qi];
    __syncthreads();
    float coef = accum ? softmax3(fw3, fsel) : 0.f;
    int j2 = threadIdx.x & 63;
    int rg = threadIdx.x >> 6;
    const float4* W0 = (const float4*)(W + (size_t)j2 * DIM);
    const float4* W1 = (const float4*)(W + (size_t)(j2 + 64) * DIM);
    float acc0[8], acc1[8];
    #pragma unroll
    for (int m = 0; m < 8; m++) { acc0[m] = 0.f; acc1[m] = 0.f; }
    for (int kq = 0; kq < 32; kq++) {
        float4 w0 = W0[kq];
        float4 w1 = W1[kq];
        #pragma unroll
        for (int m = 0; m < 8; m++) {
            float4 a = Al4[(rg + 4 * m) * 32 + kq];
            acc0[m] = fmaf(a.x, w0.x, acc0[m]); acc0[m] = fmaf(a.y, w0.y, acc0[m]);
            acc0[m] = fmaf(a.z, w0.z, acc0[m]); acc0[m] = fmaf(a.w, w0.w, acc0[m]);
            acc1[m] = fmaf(a.x, w1.x, acc1[m]); acc1[m] = fmaf(a.y, w1.y, acc1[m]);
            acc1[m] = fmaf(a.z, w1.z, acc1[m]); acc1[m] = fmaf(a.w, w1.w, acc1[m]);
        }
    }
    #pragma unroll
    for (int m = 0; m < 8; m++) {
        int i = i0 + rg + 4 * m;
        if (i >= M) continue;
        size_t o0 = (size_t)i * DIM + j2;
        size_t o1 = o0 + 64;
        if (store) { store[o0] = acc0[m]; store[o1] = acc1[m]; }
        if (accum) {
            float p0 = first ? 0.f : accum[o0];
            float p1 = first ? 0.f : accum[o1];
            accum[o0] = p0 + coef * acc0[m];
            accum[o1] = p1 + coef * acc1[m];
        }
    }
}

// ---------------- 256 selected rows of uf = su @ Wu^T ----------------
__global__ void ufsel_kernel(const float* __restrict__ su, const float* __restrict__ W,
                             const int* __restrict__ uidx, float* __restrict__ outsel) {
    int b = blockIdx.x, j = threadIdx.x;  // block 128
    __shared__ float ar[128];
    int u = iclamp(uidx[b], 0, N_USERS - 1);
    ar[j] = su[(size_t)u * DIM + j];
    __syncthreads();
    const float4* Wr = (const float4*)(W + (size_t)j * DIM);
    float acc = 0.f;
    #pragma unroll 8
    for (int q = 0; q < 32; q++) {
        float4 wq = Wr[q];
        acc = fmaf(ar[4 * q + 0], wq.x, acc);
        acc = fmaf(ar[4 * q + 1], wq.y, acc);
        acc = fmaf(ar[4 * q + 2], wq.z, acc);
        acc = fmaf(ar[4 * q + 3], wq.w, acc);
    }
    outsel[(size_t)b * DIM + j] = acc;
}

// ---------------- alt[b,j] (+)= wn_c * dot(uf_c[b], pf_c[poi]) ----------------
__global__ __launch_bounds__(256) void predict_kernel(
        const float* __restrict__ ufs, const float* __restrict__ pf,
        const int* __restrict__ pidx, const float* __restrict__ w3,
        int wsel, int first, float* __restrict__ alt) {
    int wid = (blockIdx.x * blockDim.x + threadIdx.x) >> 6;
    int lane = threadIdx.x & 63;
    if (wid >= BATCH * NPOS) return;
    int b = wid / NPOS;
    int poi = iclamp(pidx[wid], 0, N_POIS - 1);
    const float2 uv = *(const float2*)(ufs + (size_t)b * DIM + lane * 2);
    const float2 pv = *(const float2*)(pf + (size_t)poi * DIM + lane * 2);
    float s = uv.x * pv.x + uv.y * pv.y;
    #pragma unroll
    for (int o = 32; o > 0; o >>= 1) s += __shfl_xor(s, o, 64);
    if (lane == 0) {
        float coef = softmax3(w3, wsel);
        float prev = first ? 0.f : alt[wid];
        alt[wid] = prev + coef * s;
    }
}

// ---------------- BCE loss ----------------
__global__ void loss_kernel(const float* __restrict__ alt, const float* __restrict__ labels,
                            float* __restrict__ out) {
    __shared__ float red[256];
    float s = 0.f;
    for (int i = threadIdx.x; i < BATCH * NPOS; i += 256) {
        float x = alt[i], y = labels[i];
        s += fmaxf(x, 0.f) - x * y + log1pf(expf(-fabsf(x)));
    }
    red[threadIdx.x] = s;
    __syncthreads();
    for (int off = 128; off > 0; off >>= 1) {
        if (threadIdx.x < off) red[threadIdx.x] += red[threadIdx.x + off];
        __syncthreads();
    }
    if (threadIdx.x == 0) out[0] = red[0] / (float)(BATCH * NPOS);
}

// ---------------- bst[j][b] = id_feat[cur[b]] @ Ws^T + bias (transposed) ----------------
__global__ void bs_kernel(const float* __restrict__ idf, const float* __restrict__ Ws,
                          const float* __restrict__ bias, const int* __restrict__ uidx,
                          float* __restrict__ bst) {
    int b = blockIdx.x, j = threadIdx.x;  // block 128
    __shared__ float ar[128];
    int u = iclamp(uidx[b], 0, N_USERS - 1);
    ar[j] = idf[(size_t)u * DIM + j];
    __syncthreads();
    const float4* Wr = (const float4*)(Ws + (size_t)j * DIM);
    float acc = 0.f;
    #pragma unroll 8
    for (int q = 0; q < 32; q++) {
        float4 wq = Wr[q];
        acc = fmaf(ar[4 * q + 0], wq.x, acc);
        acc = fmaf(ar[4 * q + 1], wq.y, acc);
        acc = fmaf(ar[4 * q + 2], wq.z, acc);
        acc = fmaf(ar[4 * q + 3], wq.w, acc);
    }
    bst[(size_t)j * BATCH + b] = acc + bias[j];
}

__device__ __forceinline__ void topk_insert(float s, int u, float* ts, int* ti) {
    if (s > ts[TOPK - 1]) {
        #pragma unroll
        for (int j = TOPK - 1; j > 0; --j) {
            bool above = s > ts[j - 1];
            bool here = (!above) && (s > ts[j]);
            float nv = above ? ts[j - 1] : (here ? s : ts[j]);
            int ni = above ? ti[j - 1] : (here ? u : ti[j]);
            ts[j] = nv; ti[j] = ni;
        }
        if (s > ts[0]) { ts[0] = s; ti[0] = u; }
    }
}

// ---------------- fused uu scores + per-block top-20: 32 KB LDS, 1024 blocks (4/CU) ----------------
__global__ __launch_bounds__(256) void score_topk_kernel(
        const float* __restrict__ idf, const float* __restrict__ bst,
        float* __restrict__ cand_s, int* __restrict__ cand_i) {
    __shared__ __align__(16) unsigned char smraw[32768];
    float* bsl = (float*)smraw;                             // phase 1: [q][b][4] 32 KB
    float* ms  = (float*)smraw;                             // phase 2: [k][tid] 20 KB
    unsigned short* mi = (unsigned short*)(smraw + 20480);  // phase 2: [k][tid] u16 10 KB
    int cid = blockIdx.x, bg = blockIdx.y;
    for (int idx = threadIdx.x; idx < 32 * 64; idx += 256) {
        int b = idx & 63, q = idx >> 6;
        float4 v;
        v.x = bst[(size_t)(4 * q + 0) * BATCH + bg * 64 + b];
        v.y = bst[(size_t)(4 * q + 1) * BATCH + bg * 64 + b];
        v.z = bst[(size_t)(4 * q + 2) * BATCH + bg * 64 + b];
        v.w = bst[(size_t)(4 * q + 3) * BATCH + bg * 64 + b];
        *(float4*)&bsl[(size_t)idx * 4] = v;
    }
    __syncthreads();
    int b_l = threadIdx.x & 63, us = threadIdx.x >> 6;
    const float4* bcol = (const float4*)&bsl[b_l * 4];
    float ts[TOPK]; int ti[TOPK];
    #pragma unroll
    for (int k = 0; k < TOPK; k++) { ts[k] = -3.0e38f; ti[k] = 0; }
    int lo = cid * CPT;
    int hi = lo + CPT; if (hi > N_USERS) hi = N_USERS;
    for (int u0 = lo + us * 4; u0 < hi; u0 += 16) {
        int uc1 = u0 + 1 < N_USERS ? u0 + 1 : N_USERS - 1;
        int uc2 = u0 + 2 < N_USERS ? u0 + 2 : N_USERS - 1;
        int uc3 = u0 + 3 < N_USERS ? u0 + 3 : N_USERS - 1;
        const float4* r0 = (const float4*)(idf + (size_t)u0 * DIM);
        const float4* r1 = (const float4*)(idf + (size_t)uc1 * DIM);
        const float4* r2 = (const float4*)(idf + (size_t)uc2 * DIM);
        const float4* r3 = (const float4*)(idf + (size_t)uc3 * DIM);
        float s0 = 0.f, s1 = 0.f, s2 = 0.f, s3 = 0.f;
        #pragma unroll 8
        for (int q = 0; q < 32; q++) {
            float4 bb = bcol[q * 64];
            float4 a0 = r0[q], a1 = r1[q], a2 = r2[q], a3 = r3[q];
            s0 = fmaf(a0.x, bb.x, fmaf(a0.y, bb.y, fmaf(a0.z, bb.z, fmaf(a0.w, bb.w, s0))));
            s1 = fmaf(a1.x, bb.x, fmaf(a1.y, bb.y, fmaf(a1.z, bb.z, fmaf(a1.w, bb.w, s1))));
            s2 = fmaf(a2.x, bb.x, fmaf(a2.y, bb.y, fmaf(a2.z, bb.z, fmaf(a2.w, bb.w, s2))));
            s3 = fmaf(a3.x, bb.x, fmaf(a3.y, bb.y, fmaf(a3.z, bb.z, fmaf(a3.w, bb.w, s3))));
        }
        topk_insert(s0, u0, ts, ti);
        if (u0 + 1 < hi) topk_insert(s1, u0 + 1, ts, ti);
        if (u0 + 2 < hi) topk_insert(s2, u0 + 2, ts, ti);
        if (u0 + 3 < hi) topk_insert(s3, u0 + 3, ts, ti);
    }
    __syncthreads();
    #pragma unroll
    for (int k = 0; k < TOPK; k++) {
        ms[k * 256 + threadIdx.x] = ts[k];
        mi[k * 256 + threadIdx.x] = (unsigned short)ti[k];
    }
    __syncthreads();
    if (threadIdx.x < 64) {
        int t = threadIdx.x;
        int p0 = 0, p1 = 0, p2 = 0, p3 = 0;
        size_t ob = (((size_t)cid) * 256 + bg * 64 + t) * TOPK;
        for (int k = 0; k < TOPK; k++) {
            float h0 = ms[p0 * 256 + 0 * 64 + t];
            float h1 = ms[p1 * 256 + 1 * 64 + t];
            float h2 = ms[p2 * 256 + 2 * 64 + t];
            float h3 = ms[p3 * 256 + 3 * 64 + t];
            float best = h0; int which = 0;
            if (h1 > best) { best = h1; which = 1; }
            if (h2 > best) { best = h2; which = 2; }
            if (h3 > best) { best = h3; which = 3; }
            int idx;
            if (which == 0)      { idx = mi[p0 * 256 + 0 * 64 + t]; p0++; }
            else if (which == 1) { idx = mi[p1 * 256 + 1 * 64 + t]; p1++; }
            else if (which == 2) { idx = mi[p2 * 256 + 2 * 64 + t]; p2++; }
            else                 { idx = mi[p3 * 256 + 3 * 64 + t]; p3++; }
            cand_s[ob + k] = best;
            cand_i[ob + k] = idx;
        }
    }
}

// ---------------- global merge (256 chunks) + softmax + weighted gather ----------------
__global__ void topk_merge_kernel(const float* __restrict__ cand_s, const int* __restrict__ cand_i,
                                  const float* __restrict__ guf,
                                  float* __restrict__ outp) {
    int b = blockIdx.x, t = threadIdx.x;  // block 256 (= NCHUNK)
    __shared__ float rs[256]; __shared__ int ru[256]; __shared__ int rt[256];
    __shared__ float win_s[TOPK]; __shared__ int win_u[TOPK]; __shared__ float wk[TOPK];
    __shared__ int winner;
    int ptr = 0;
    size_t base = ((size_t)t * 256 + b) * TOPK;
    for (int k = 0; k < TOPK; k++) {
        rs[t] = (ptr < TOPK) ? cand_s[base + ptr] : -3.0e38f;
        ru[t] = (ptr < TOPK) ? cand_i[base + ptr] : 0;
        rt[t] = t;
        __syncthreads();
        for (int off = 128; off > 0; off >>= 1) {
            if (t < off && rs[t + off] > rs[t]) {
                rs[t] = rs[t + off]; ru[t] = ru[t + off]; rt[t] = rt[t + off];
            }
            __syncthreads();
        }
        if (t == 0) { win_s[k] = rs[0]; win_u[k] = iclamp(ru[0], 0, N_USERS - 1); winner = rt[0]; }
        __syncthreads();
        if (t == winner) ptr++;
        __syncthreads();
    }
    if (t == 0) {
        float m = win_s[0], den = 0.f;
        for (int k = 0; k < TOPK; k++) { wk[k] = expf(win_s[k] - m); den += wk[k]; }
        float inv = 1.f / den;
        for (int k = 0; k < TOPK; k++) wk[k] *= inv;
    }
    __syncthreads();
    if (t < DIM) {
        float acc = 0.f;
        #pragma unroll
        for (int k = 0; k < TOPK; k++)
            acc = fmaf(wk[k], guf[(size_t)win_u[k] * DIM + t], acc);
        outp[1 + (size_t)b * DIM + t] = acc;
    }
}

extern "C" void kernel_launch(void* const* d_in, const int* in_sizes, int n_in,
                              void* d_out, int out_size, void* d_ws, size_t ws_size,
                              hipStream_t stream) {
    (void)in_sizes; (void)n_in; (void)out_size; (void)ws_size;
    const int*   er      = (const int*)d_in[0];
    const int*   ec      = (const int*)d_in[1];
    const float* click   = (const float*)d_in[2];
    const float* favor   = (const float*)d_in[3];
    const float* consume = (const float*)d_in[4];
    const float* uid     = (const float*)d_in[5];
    const float* pid     = (const float*)d_in[6];
    const int*   uidx    = (const int*)d_in[7];
    const int*   pidx    = (const int*)d_in[8];
    const float* labels  = (const float*)d_in[9];
    const float* guf     = (const float*)d_in[10];
    const float* w3      = (const float*)d_in[11];
    const float* fw3     = (const float*)d_in[12];
    const float* Wuc     = (const float*)d_in[13];
    const float* Wpc     = (const float*)d_in[14];
    const float* Wufv    = (const float*)d_in[15];
    const float* Wpfv    = (const float*)d_in[16];
    const float* Wuco    = (const float*)d_in[17];
    const float* Wpco    = (const float*)d_in[18];
    const float* Wss     = (const float*)d_in[19];
    const float* bias    = (const float*)d_in[20];
    float* outp = (float*)d_out;

    char* ws = (char*)d_ws;
    size_t off = 0;
    auto carve = [&](size_t bytes) -> void* {
        off = (off + 255) & ~(size_t)255;
        void* p = ws + off;
        off += bytes;
        return p;
    };
    // total ~84 MB (proven-safe range)
    float* ufs = (float*)carve(4ll * 3 * BATCH * DIM);
    float* alt = (float*)carve(4ll * BATCH * NPOS);
    float* bst = (float*)carve(4ll * DIM * BATCH);
    int* rptr = (int*)carve(4 * (N_USERS + 1));
    int* cptr = (int*)carve(4 * (N_POIS + 1));
    int* cnts = (int*)carve(4 * (2 * (N_USERS + N_POIS)));
    int* rcnt = cnts;
    int* ccnt = cnts + N_USERS;
    int* rcur = ccnt + N_POIS;
    int* ccur = rcur + N_USERS;
    int* rcols = (int*)carve(4 * (size_t)N_EDGES);
    int* crows = (int*)carve(4 * (size_t)N_EDGES);
    float* rv[3]; float* cv[3];
    for (int c = 0; c < 3; c++) rv[c] = (float*)carve(4 * (size_t)N_EDGES);
    for (int c = 0; c < 3; c++) cv[c] = (float*)carve(4 * (size_t)N_EDGES);
    unsigned short* pid_b = (unsigned short*)carve(2ll * N_POIS * DIM);
    unsigned short* utr_b = (unsigned short*)carve(2ll * N_USERS * DIM);  // 10.24 MB; pf alias
    unsigned short* ptr_b = (unsigned short*)carve(2ll * N_POIS * DIM);
    float* su  = (float*)carve(4ll * N_USERS * DIM);   // cand alias (10.5 MB <= 20.5 MB)
    float* sp  = (float*)carve(4ll * N_POIS * DIM);
    float* idf = (float*)carve(4ll * N_USERS * DIM);
    float* pf = (float*)utr_b;            // utr_b (10.24 MB) dead before pf (10.24 MB) written
    float* cand_s = su;                   // su dead before score_topk
    int*   cand_i = (int*)(su + (size_t)NCHUNK * BATCH * TOPK);

    zero_kernel<<<(2 * (N_USERS + N_POIS) + 255) / 256, 256, 0, stream>>>(
        (unsigned int*)cnts, 2 * (N_USERS + N_POIS));
    cast_bf16_kernel<<<(N_POIS * DIM / 2 + 255) / 256, 256, 0, stream>>>(pid, pid_b, N_POIS * DIM / 2);
    hist_kernel<<<(N_EDGES + 255) / 256, 256, 0, stream>>>(er, ec, rcnt, ccnt);
    scan_kernel<<<2, 256, 0, stream>>>(rcnt, rptr, ccnt, cptr);
    fill_kernel<<<(N_EDGES + 255) / 256, 256, 0, stream>>>(
        er, ec, rptr, cptr, rcur, ccur, rcols, crows,
        click, favor, consume, rv[0], rv[1], rv[2], cv[0], cv[1], cv[2]);

    struct Ch { const float* Wu; const float* Wp; int wsel; int fsel; };
    // wn (softmax over w[1,3]):  favor=0, click=1, consume=2
    // fwn (softmax over fw[3,1]): favor=0, consume=1, click=2
    Ch chs[3] = { { Wuc,  Wpc,  1, 2 },     // ch0 = click
                  { Wufv, Wpfv, 0, 0 },     // ch1 = favor
                  { Wuco, Wpco, 2, 1 } };   // ch2 = consume

    for (int c = 0; c < 3; c++) {
        // layer 1: u1 = A p0 ; su = uid + n(u1).  p1 = A^T u1 ; sp = pid + n(p1)
        spmm_kernel<<<N_USERS * 64 / 256, 256, 0, stream>>>(rptr, rcols, rv[c], pid_b, utr_b, uid, su, N_USERS);
        spmm_kernel<<<N_POIS * 64 / 256, 256, 0, stream>>>(cptr, crows, cv[c], utr_b, ptr_b, pid, sp, N_POIS);
        // layer 2
        spmm_kernel<<<N_USERS * 64 / 256, 256, 0, stream>>>(rptr, rcols, rv[c], ptr_b, utr_b, su, su, N_USERS);
        spmm_kernel<<<N_POIS * 64 / 256, 256, 0, stream>>>(cptr, crows, cv[c], utr_b, ptr_b, sp, sp, N_POIS);
        // idf (+)= fwn_c * (su @ Wu^T)
        gemm_aw_kernel<<<N_USERS / 32, 256, 0, stream>>>(su, chs[c].Wu, nullptr, idf, fw3, chs[c].fsel, (c == 0) ? 1 : 0, N_USERS);
        ufsel_kernel<<<BATCH, 128, 0, stream>>>(su, chs[c].Wu, uidx, ufs + (size_t)c * BATCH * DIM);
        // pf = sp @ Wp^T  (pf aliases utr_b, dead after L2 poi hop)
        gemm_aw_kernel<<<N_POIS / 32, 256, 0, stream>>>(sp, chs[c].Wp, pf, nullptr, fw3, 0, 0, N_POIS);
        predict_kernel<<<BATCH * NPOS * 64 / 256, 256, 0, stream>>>(
            ufs + (size_t)c * BATCH * DIM, pf, pidx, w3, chs[c].wsel, (c == 0) ? 1 : 0, alt);
    }

    loss_kernel<<<1, 256, 0, stream>>>(alt, labels, outp);
    bs_kernel<<<BATCH, 128, 0, stream>>>(idf, Wss, bias, uidx, bst);
    dim3 sg(NCHUNK, 4);
    score_topk_kernel<<<sg, 256, 0, stream>>>(idf, bst, cand_s, cand_i);
    topk_merge_kernel<<<BATCH, 256, 0, stream>>>(cand_s, cand_i, guf, outp);
}

// Round 11
// 1086.073 us; speedup vs baseline: 1.2026x; 1.0588x over previous
//
#include <hip/hip_runtime.h>

#define N_USERS 40000
#define N_POIS  20000
#define DIM     128
#define N_EDGES 500000
#define BATCH   256
#define NPOS    100
#define TOPK    20
#define NCHUNK  128
#define CPT     313   // ceil(40000/128)

__device__ __forceinline__ int iclamp(int x, int lo, int hi) {
    return x < lo ? lo : (x > hi ? hi : x);
}
__device__ __forceinline__ float2 h2f2(unsigned int u) {
    union { unsigned int u32; _Float16 h[2]; } v; v.u32 = u;
    return make_float2((float)v.h[0], (float)v.h[1]);
}
__device__ __forceinline__ unsigned int f2h2(float x, float y) {
    union { unsigned int u32; _Float16 h[2]; } v;
    v.h[0] = (_Float16)x; v.h[1] = (_Float16)y; return v.u32;
}
__device__ __forceinline__ float softmax3(const float* p, int sel) {
    float a0 = p[0], a1 = p[1], a2 = p[2];
    float m = fmaxf(a0, fmaxf(a1, a2));
    float e0 = expf(a0 - m), e1 = expf(a1 - m), e2 = expf(a2 - m);
    float den = e0 + e1 + e2;
    float e = (sel == 0) ? e0 : ((sel == 1) ? e1 : e2);
    return e / den;
}

// ---------------- zero init ----------------
__global__ void zero_kernel(unsigned int* __restrict__ p, int nwords) {
    int i = blockIdx.x * blockDim.x + threadIdx.x;
    if (i < nwords) p[i] = 0u;
}

// ---------------- fp32 -> fp16 cast ----------------
__global__ void cast_f16_kernel(const float* __restrict__ src, unsigned short* __restrict__ dst,
                                int n2) {
    int i = blockIdx.x * blockDim.x + threadIdx.x;
    if (i < n2) {
        float2 v = *(const float2*)(src + 2 * (size_t)i);
        *(unsigned int*)(dst + 2 * (size_t)i) = f2h2(v.x, v.y);
    }
}

// ---------------- CSR build ----------------
__global__ void hist_kernel(const int* __restrict__ er, const int* __restrict__ ec,
                            int* __restrict__ rcnt, int* __restrict__ ccnt) {
    int e = blockIdx.x * blockDim.x + threadIdx.x;
    if (e < N_EDGES) {
        atomicAdd(&rcnt[iclamp(er[e], 0, N_USERS - 1)], 1);
        atomicAdd(&ccnt[iclamp(ec[e], 0, N_POIS - 1)], 1);
    }
}

__global__ void scan_kernel(const int* __restrict__ rcnt, int* __restrict__ rptr,
                            const int* __restrict__ ccnt, int* __restrict__ cptr) {
    const int* cnt = blockIdx.x ? ccnt : rcnt;
    int* ptr = blockIdx.x ? cptr : rptr;
    int n = blockIdx.x ? N_POIS : N_USERS;
    __shared__ int part[256];
    __shared__ int pref[257];
    int C = (n + 255) / 256;
    int lo = threadIdx.x * C;
    int hi = lo + C; if (hi > n) hi = n;
    int s = 0;
    for (int i = lo; i < hi; i++) s += cnt[i];
    part[threadIdx.x] = s;
    __syncthreads();
    if (threadIdx.x == 0) {
        int r = 0;
        for (int i = 0; i < 256; i++) { pref[i] = r; r += part[i]; }
        pref[256] = r;
    }
    __syncthreads();
    int r = pref[threadIdx.x];
    for (int i = lo; i < hi; i++) { ptr[i] = r; r += cnt[i]; }
    if (threadIdx.x == 0) ptr[n] = pref[256];
}

__global__ void fill_kernel(const int* __restrict__ er, const int* __restrict__ ec,
                            const int* __restrict__ rptr, const int* __restrict__ cptr,
                            int* __restrict__ rcur, int* __restrict__ ccur,
                            int* __restrict__ rcols, int* __restrict__ crows,
                            const float* __restrict__ ck, const float* __restrict__ fv,
                            const float* __restrict__ cs,
                            float* __restrict__ rv0, float* __restrict__ rv1, float* __restrict__ rv2,
                            float* __restrict__ cv0, float* __restrict__ cv1, float* __restrict__ cv2) {
    int e = blockIdx.x * blockDim.x + threadIdx.x;
    if (e < N_EDGES) {
        int r = iclamp(er[e], 0, N_USERS - 1), c = iclamp(ec[e], 0, N_POIS - 1);
        float v0 = ck[e], v1 = fv[e], v2 = cs[e];
        int pr = iclamp(rptr[r] + atomicAdd(&rcur[r], 1), 0, N_EDGES - 1);
        rcols[pr] = c; rv0[pr] = v0; rv1[pr] = v1; rv2[pr] = v2;
        int pc = iclamp(cptr[c] + atomicAdd(&ccur[c], 1), 0, N_EDGES - 1);
        crows[pc] = r; cv0[pc] = v0; cv1[pc] = v1; cv2[pc] = v2;
    }
}

// ---------------- SpMM: one wave per row; fp16 src gather; predicated tail batch ----------------
// raw_h (fp16) = A*src ; acc (fp32) = base + raw/||raw||
__global__ __launch_bounds__(256) void spmm_kernel(
        const int* __restrict__ ptr, const int* __restrict__ nbr,
        const float* __restrict__ vals,                 // CSR-ordered
        const unsigned short* __restrict__ src,         // fp16 [*,128]
        unsigned short* __restrict__ raw_h,             // fp16 out
        const float* __restrict__ base,                 // fp32 (may alias acc)
        float* __restrict__ acc, int nrows) {
    int wid = (blockIdx.x * blockDim.x + threadIdx.x) >> 6;
    int lane = threadIdx.x & 63;
    if (wid >= nrows) return;
    int beg = __builtin_amdgcn_readfirstlane(iclamp(ptr[wid], 0, N_EDGES));
    int end = __builtin_amdgcn_readfirstlane(iclamp(ptr[wid + 1], 0, N_EDGES));
    if (end < beg) end = beg;
    float ax = 0.f, ay = 0.f;
    int e = beg;
    int lo2 = lane * 2;
    for (; e + 8 <= end; e += 8) {
        int c0 = nbr[e + 0], c1 = nbr[e + 1], c2 = nbr[e + 2], c3 = nbr[e + 3];
        int c4 = nbr[e + 4], c5 = nbr[e + 5], c6 = nbr[e + 6], c7 = nbr[e + 7];
        float v0 = vals[e + 0], v1 = vals[e + 1], v2 = vals[e + 2], v3 = vals[e + 3];
        float v4 = vals[e + 4], v5 = vals[e + 5], v6 = vals[e + 6], v7 = vals[e + 7];
        float2 p0 = h2f2(*(const unsigned int*)(src + (size_t)c0 * DIM + lo2));
        float2 p1 = h2f2(*(const unsigned int*)(src + (size_t)c1 * DIM + lo2));
        float2 p2 = h2f2(*(const unsigned int*)(src + (size_t)c2 * DIM + lo2));
        float2 p3 = h2f2(*(const unsigned int*)(src + (size_t)c3 * DIM + lo2));
        float2 p4 = h2f2(*(const unsigned int*)(src + (size_t)c4 * DIM + lo2));
        float2 p5 = h2f2(*(const unsigned int*)(src + (size_t)c5 * DIM + lo2));
        float2 p6 = h2f2(*(const unsigned int*)(src + (size_t)c6 * DIM + lo2));
        float2 p7 = h2f2(*(const unsigned int*)(src + (size_t)c7 * DIM + lo2));
        ax = fmaf(v0, p0.x, fmaf(v1, p1.x, fmaf(v2, p2.x, fmaf(v3, p3.x, ax))));
        ax = fmaf(v4, p4.x, fmaf(v5, p5.x, fmaf(v6, p6.x, fmaf(v7, p7.x, ax))));
        ay = fmaf(v0, p0.y, fmaf(v1, p1.y, fmaf(v2, p2.y, fmaf(v3, p3.y, ay))));
        ay = fmaf(v4, p4.y, fmaf(v5, p5.y, fmaf(v6, p6.y, fmaf(v7, p7.y, ay))));
    }
    if (e < end) {
        // branchless predicated batch of up to 8 — all loads in flight before any FMA
        int last = end - 1;
        int e1 = e + 1 <= last ? e + 1 : last;
        int e2 = e + 2 <= last ? e + 2 : last;
        int e3 = e + 3 <= last ? e + 3 : last;
        int e4 = e + 4 <= last ? e + 4 : last;
        int e5 = e + 5 <= last ? e + 5 : last;
        int e6 = e + 6 <= last ? e + 6 : last;
        int e7 = e + 7 <= last ? e + 7 : last;
        int c0 = nbr[e], c1 = nbr[e1], c2 = nbr[e2], c3 = nbr[e3];
        int c4 = nbr[e4], c5 = nbr[e5], c6 = nbr[e6], c7 = nbr[e7];
        float v0 = vals[e];
        float v1 = (e + 1 < end) ? vals[e1] : 0.f;
        float v2 = (e + 2 < end) ? vals[e2] : 0.f;
        float v3 = (e + 3 < end) ? vals[e3] : 0.f;
        float v4 = (e + 4 < end) ? vals[e4] : 0.f;
        float v5 = (e + 5 < end) ? vals[e5] : 0.f;
        float v6 = (e + 6 < end) ? vals[e6] : 0.f;
        float v7 = (e + 7 < end) ? vals[e7] : 0.f;
        float2 p0 = h2f2(*(const unsigned int*)(src + (size_t)c0 * DIM + lo2));
        float2 p1 = h2f2(*(const unsigned int*)(src + (size_t)c1 * DIM + lo2));
        float2 p2 = h2f2(*(const unsigned int*)(src + (size_t)c2 * DIM + lo2));
        float2 p3 = h2f2(*(const unsigned int*)(src + (size_t)c3 * DIM + lo2));
        float2 p4 = h2f2(*(const unsigned int*)(src + (size_t)c4 * DIM + lo2));
        float2 p5 = h2f2(*(const unsigned int*)(src + (size_t)c5 * DIM + lo2));
        float2 p6 = h2f2(*(const unsigned int*)(src + (size_t)c6 * DIM + lo2));
        float2 p7 = h2f2(*(const unsigned int*)(src + (size_t)c7 * DIM + lo2));
        ax = fmaf(v0, p0.x, fmaf(v1, p1.x, fmaf(v2, p2.x, fmaf(v3, p3.x, ax))));
        ax = fmaf(v4, p4.x, fmaf(v5, p5.x, fmaf(v6, p6.x, fmaf(v7, p7.x, ax))));
        ay = fmaf(v0, p0.y, fmaf(v1, p1.y, fmaf(v2, p2.y, fmaf(v3, p3.y, ay))));
        ay = fmaf(v4, p4.y, fmaf(v5, p5.y, fmaf(v6, p6.y, fmaf(v7, p7.y, ay))));
    }
    float n2 = ax * ax + ay * ay;
    #pragma unroll
    for (int o = 32; o > 0; o >>= 1) n2 += __shfl_xor(n2, o, 64);
    float inv = rsqrtf(fmaxf(n2, 1e-30f));
    *(unsigned int*)(raw_h + (size_t)wid * DIM + lo2) = f2h2(ax, ay);
    float2 bv = *(const float2*)(base + (size_t)wid * DIM + lo2);
    *(float2*)(acc + (size_t)wid * DIM + lo2) =
        make_float2(bv.x + ax * inv, bv.y + ay * inv);
}

// ---------------- out = A[Mx128] @ W^T ; A-tile in LDS ----------------
__global__ __launch_bounds__(256) void gemm_aw_kernel(
        const float* __restrict__ A, const float* __restrict__ W,
        float* __restrict__ store, float* __restrict__ accum,
        const float* __restrict__ fw3, int fsel, int first, int M) {
    __shared__ float Al[32 * 128];                 // 16 KB
    int i0 = blockIdx.x * 32;
    const float4* Ag = (const float4*)(A + (size_t)i0 * DIM);
    float4* Al4 = (float4*)Al;
    for (int qi = threadIdx.x; qi < 1024; qi += 256) Al4[qi] = Ag[qi];
    __syncthreads();
    float coef = accum ? softmax3(fw3, fsel) : 0.f;
    int j2 = threadIdx.x & 63;
    int rg = threadIdx.x >> 6;
    const float4* W0 = (const float4*)(W + (size_t)j2 * DIM);
    const float4* W1 = (const float4*)(W + (size_t)(j2 + 64) * DIM);
    float acc0[8], acc1[8];
    #pragma unroll
    for (int m = 0; m < 8; m++) { acc0[m] = 0.f; acc1[m] = 0.f; }
    for (int kq = 0; kq < 32; kq++) {
        float4 w0 = W0[kq];
        float4 w1 = W1[kq];
        #pragma unroll
        for (int m = 0; m < 8; m++) {
            float4 a = Al4[(rg + 4 * m) * 32 + kq];
            acc0[m] = fmaf(a.x, w0.x, acc0[m]); acc0[m] = fmaf(a.y, w0.y, acc0[m]);
            acc0[m] = fmaf(a.z, w0.z, acc0[m]); acc0[m] = fmaf(a.w, w0.w, acc0[m]);
            acc1[m] = fmaf(a.x, w1.x, acc1[m]); acc1[m] = fmaf(a.y, w1.y, acc1[m]);
            acc1[m] = fmaf(a.z, w1.z, acc1[m]); acc1[m] = fmaf(a.w, w1.w, acc1[m]);
        }
    }
    #pragma unroll
    for (int m = 0; m < 8; m++) {
        int i = i0 + rg + 4 * m;
        if (i >= M) continue;
        size_t o0 = (size_t)i * DIM + j2;
        size_t o1 = o0 + 64;
        if (store) { store[o0] = acc0[m]; store[o1] = acc1[m]; }
        if (accum) {
            float p0 = first ? 0.f : accum[o0];
            float p1 = first ? 0.f : accum[o1];
            accum[o0] = p0 + coef * acc0[m];
            accum[o1] = p1 + coef * acc1[m];
        }
    }
}

// ---------------- 256 selected rows of uf = su @ Wu^T ----------------
__global__ void ufsel_kernel(const float* __restrict__ su, const float* __restrict__ W,
                             const int* __restrict__ uidx, float* __restrict__ outsel) {
    int b = blockIdx.x, j = threadIdx.x;  // block 128
    __shared__ float ar[128];
    int u = iclamp(uidx[b], 0, N_USERS - 1);
    ar[j] = su[(size_t)u * DIM + j];
    __syncthreads();
    const float4* Wr = (const float4*)(W + (size_t)j * DIM);
    float acc = 0.f;
    #pragma unroll 8
    for (int q = 0; q < 32; q++) {
        float4 wq = Wr[q];
        acc = fmaf(ar[4 * q + 0], wq.x, acc);
        acc = fmaf(ar[4 * q + 1], wq.y, acc);
        acc = fmaf(ar[4 * q + 2], wq.z, acc);
        acc = fmaf(ar[4 * q + 3], wq.w, acc);
    }
    outsel[(size_t)b * DIM + j] = acc;
}

// ---------------- alt[b,j] (+)= wn_c * dot(uf_c[b], pf_c[poi]) ----------------
__global__ __launch_bounds__(256) void predict_kernel(
        const float* __restrict__ ufs, const float* __restrict__ pf,
        const int* __restrict__ pidx, const float* __restrict__ w3,
        int wsel, int first, float* __restrict__ alt) {
    int wid = (blockIdx.x * blockDim.x + threadIdx.x) >> 6;
    int lane = threadIdx.x & 63;
    if (wid >= BATCH * NPOS) return;
    int b = wid / NPOS;
    int poi = iclamp(pidx[wid], 0, N_POIS - 1);
    const float2 uv = *(const float2*)(ufs + (size_t)b * DIM + lane * 2);
    const float2 pv = *(const float2*)(pf + (size_t)poi * DIM + lane * 2);
    float s = uv.x * pv.x + uv.y * pv.y;
    #pragma unroll
    for (int o = 32; o > 0; o >>= 1) s += __shfl_xor(s, o, 64);
    if (lane == 0) {
        float coef = softmax3(w3, wsel);
        float prev = first ? 0.f : alt[wid];
        alt[wid] = prev + coef * s;
    }
}

// ---------------- BCE loss ----------------
__global__ void loss_kernel(const float* __restrict__ alt, const float* __restrict__ labels,
                            float* __restrict__ out) {
    __shared__ float red[256];
    float s = 0.f;
    for (int i = threadIdx.x; i < BATCH * NPOS; i += 256) {
        float x = alt[i], y = labels[i];
        s += fmaxf(x, 0.f) - x * y + log1pf(expf(-fabsf(x)));
    }
    red[threadIdx.x] = s;
    __syncthreads();
    for (int off = 128; off > 0; off >>= 1) {
        if (threadIdx.x < off) red[threadIdx.x] += red[threadIdx.x + off];
        __syncthreads();
    }
    if (threadIdx.x == 0) out[0] = red[0] / (float)(BATCH * NPOS);
}

// ---------------- bst[j][b] = id_feat[cur[b]] @ Ws^T + bias (transposed) ----------------
__global__ void bs_kernel(const float* __restrict__ idf, const float* __restrict__ Ws,
                          const float* __restrict__ bias, const int* __restrict__ uidx,
                          float* __restrict__ bst) {
    int b = blockIdx.x, j = threadIdx.x;  // block 128
    __shared__ float ar[128];
    int u = iclamp(uidx[b], 0, N_USERS - 1);
    ar[j] = idf[(size_t)u * DIM + j];
    __syncthreads();
    const float4* Wr = (const float4*)(Ws + (size_t)j * DIM);
    float acc = 0.f;
    #pragma unroll 8
    for (int q = 0; q < 32; q++) {
        float4 wq = Wr[q];
        acc = fmaf(ar[4 * q + 0], wq.x, acc);
        acc = fmaf(ar[4 * q + 1], wq.y, acc);
        acc = fmaf(ar[4 * q + 2], wq.z, acc);
        acc = fmaf(ar[4 * q + 3], wq.w, acc);
    }
    bst[(size_t)j * BATCH + b] = acc + bias[j];
}

__device__ __forceinline__ void topk_insert(float s, int u, float* ts, int* ti) {
    if (s > ts[TOPK - 1]) {
        #pragma unroll
        for (int j = TOPK - 1; j > 0; --j) {
            bool above = s > ts[j - 1];
            bool here = (!above) && (s > ts[j]);
            float nv = above ? ts[j - 1] : (here ? s : ts[j]);
            int ni = above ? ti[j - 1] : (here ? u : ti[j]);
            ts[j] = nv; ti[j] = ni;
        }
        if (s > ts[0]) { ts[0] = s; ti[0] = u; }
    }
}

// ---------------- fused uu scores + per-block top-20: 32 KB LDS, NCHUNK=128 ----------------
__global__ __launch_bounds__(256) void score_topk_kernel(
        const float* __restrict__ idf, const float* __restrict__ bst,
        float* __restrict__ cand_s, int* __restrict__ cand_i) {
    __shared__ __align__(16) unsigned char smraw[32768];
    float* bsl = (float*)smraw;                             // phase 1: [q][b][4] 32 KB
    float* ms  = (float*)smraw;                             // phase 2: [k][tid] 20 KB
    unsigned short* mi = (unsigned short*)(smraw + 20480);  // phase 2: [k][tid] u16 10 KB
    int cid = blockIdx.x, bg = blockIdx.y;
    for (int idx = threadIdx.x; idx < 32 * 64; idx += 256) {
        int b = idx & 63, q = idx >> 6;
        float4 v;
        v.x = bst[(size_t)(4 * q + 0) * BATCH + bg * 64 + b];
        v.y = bst[(size_t)(4 * q + 1) * BATCH + bg * 64 + b];
        v.z = bst[(size_t)(4 * q + 2) * BATCH + bg * 64 + b];
        v.w = bst[(size_t)(4 * q + 3) * BATCH + bg * 64 + b];
        *(float4*)&bsl[(size_t)idx * 4] = v;
    }
    __syncthreads();
    int b_l = threadIdx.x & 63, us = threadIdx.x >> 6;
    const float4* bcol = (const float4*)&bsl[b_l * 4];
    float ts[TOPK]; int ti[TOPK];
    #pragma unroll
    for (int k = 0; k < TOPK; k++) { ts[k] = -3.0e38f; ti[k] = 0; }
    int lo = cid * CPT;
    int hi = lo + CPT; if (hi > N_USERS) hi = N_USERS;
    for (int u0 = lo + us * 4; u0 < hi; u0 += 16) {
        int uc1 = u0 + 1 < N_USERS ? u0 + 1 : N_USERS - 1;
        int uc2 = u0 + 2 < N_USERS ? u0 + 2 : N_USERS - 1;
        int uc3 = u0 + 3 < N_USERS ? u0 + 3 : N_USERS - 1;
        const float4* r0 = (const float4*)(idf + (size_t)u0 * DIM);
        const float4* r1 = (const float4*)(idf + (size_t)uc1 * DIM);
        const float4* r2 = (const float4*)(idf + (size_t)uc2 * DIM);
        const float4* r3 = (const float4*)(idf + (size_t)uc3 * DIM);
        float s0 = 0.f, s1 = 0.f, s2 = 0.f, s3 = 0.f;
        #pragma unroll 8
        for (int q = 0; q < 32; q++) {
            float4 bb = bcol[q * 64];
            float4 a0 = r0[q], a1 = r1[q], a2 = r2[q], a3 = r3[q];
            s0 = fmaf(a0.x, bb.x, fmaf(a0.y, bb.y, fmaf(a0.z, bb.z, fmaf(a0.w, bb.w, s0))));
            s1 = fmaf(a1.x, bb.x, fmaf(a1.y, bb.y, fmaf(a1.z, bb.z, fmaf(a1.w, bb.w, s1))));
            s2 = fmaf(a2.x, bb.x, fmaf(a2.y, bb.y, fmaf(a2.z, bb.z, fmaf(a2.w, bb.w, s2))));
            s3 = fmaf(a3.x, bb.x, fmaf(a3.y, bb.y, fmaf(a3.z, bb.z, fmaf(a3.w, bb.w, s3))));
        }
        topk_insert(s0, u0, ts, ti);
        if (u0 + 1 < hi) topk_insert(s1, u0 + 1, ts, ti);
        if (u0 + 2 < hi) topk_insert(s2, u0 + 2, ts, ti);
        if (u0 + 3 < hi) topk_insert(s3, u0 + 3, ts, ti);
    }
    __syncthreads();
    #pragma unroll
    for (int k = 0; k < TOPK; k++) {
        ms[k * 256 + threadIdx.x] = ts[k];
        mi[k * 256 + threadIdx.x] = (unsigned short)ti[k];
    }
    __syncthreads();
    if (threadIdx.x < 64) {
        int t = threadIdx.x;
        int p0 = 0, p1 = 0, p2 = 0, p3 = 0;
        size_t ob = (((size_t)cid) * 256 + bg * 64 + t) * TOPK;
        for (int k = 0; k < TOPK; k++) {
            float h0 = ms[p0 * 256 + 0 * 64 + t];
            float h1 = ms[p1 * 256 + 1 * 64 + t];
            float h2 = ms[p2 * 256 + 2 * 64 + t];
            float h3 = ms[p3 * 256 + 3 * 64 + t];
            float best = h0; int which = 0;
            if (h1 > best) { best = h1; which = 1; }
            if (h2 > best) { best = h2; which = 2; }
            if (h3 > best) { best = h3; which = 3; }
            int idx;
            if (which == 0)      { idx = mi[p0 * 256 + 0 * 64 + t]; p0++; }
            else if (which == 1) { idx = mi[p1 * 256 + 1 * 64 + t]; p1++; }
            else if (which == 2) { idx = mi[p2 * 256 + 2 * 64 + t]; p2++; }
            else                 { idx = mi[p3 * 256 + 3 * 64 + t]; p3++; }
            cand_s[ob + k] = best;
            cand_i[ob + k] = idx;
        }
    }
}

// ---------------- global merge + softmax + weighted gather ----------------
__global__ void topk_merge_kernel(const float* __restrict__ cand_s, const int* __restrict__ cand_i,
                                  const float* __restrict__ guf,
                                  float* __restrict__ outp) {
    int b = blockIdx.x, t = threadIdx.x;  // block 128 (= NCHUNK)
    __shared__ float rs[128]; __shared__ int ru[128]; __shared__ int rt[128];
    __shared__ float win_s[TOPK]; __shared__ int win_u[TOPK]; __shared__ float wk[TOPK];
    __shared__ int winner;
    int ptr = 0;
    size_t base = ((size_t)t * 256 + b) * TOPK;
    for (int k = 0; k < TOPK; k++) {
        rs[t] = (ptr < TOPK) ? cand_s[base + ptr] : -3.0e38f;
        ru[t] = (ptr < TOPK) ? cand_i[base + ptr] : 0;
        rt[t] = t;
        __syncthreads();
        for (int off = 64; off > 0; off >>= 1) {
            if (t < off && rs[t + off] > rs[t]) {
                rs[t] = rs[t + off]; ru[t] = ru[t + off]; rt[t] = rt[t + off];
            }
            __syncthreads();
        }
        if (t == 0) { win_s[k] = rs[0]; win_u[k] = iclamp(ru[0], 0, N_USERS - 1); winner = rt[0]; }
        __syncthreads();
        if (t == winner) ptr++;
        __syncthreads();
    }
    if (t == 0) {
        float m = win_s[0], den = 0.f;
        for (int k = 0; k < TOPK; k++) { wk[k] = expf(win_s[k] - m); den += wk[k]; }
        float inv = 1.f / den;
        for (int k = 0; k < TOPK; k++) wk[k] *= inv;
    }
    __syncthreads();
    float acc = 0.f;
    #pragma unroll
    for (int k = 0; k < TOPK; k++)
        acc = fmaf(wk[k], guf[(size_t)win_u[k] * DIM + t], acc);
    outp[1 + (size_t)b * DIM + t] = acc;
}

extern "C" void kernel_launch(void* const* d_in, const int* in_sizes, int n_in,
                              void* d_out, int out_size, void* d_ws, size_t ws_size,
                              hipStream_t stream) {
    (void)in_sizes; (void)n_in; (void)out_size; (void)ws_size;
    const int*   er      = (const int*)d_in[0];
    const int*   ec      = (const int*)d_in[1];
    const float* click   = (const float*)d_in[2];
    const float* favor   = (const float*)d_in[3];
    const float* consume = (const float*)d_in[4];
    const float* uid     = (const float*)d_in[5];
    const float* pid     = (const float*)d_in[6];
    const int*   uidx    = (const int*)d_in[7];
    const int*   pidx    = (const int*)d_in[8];
    const float* labels  = (const float*)d_in[9];
    const float* guf     = (const float*)d_in[10];
    const float* w3      = (const float*)d_in[11];
    const float* fw3     = (const float*)d_in[12];
    const float* Wuc     = (const float*)d_in[13];
    const float* Wpc     = (const float*)d_in[14];
    const float* Wufv    = (const float*)d_in[15];
    const float* Wpfv    = (const float*)d_in[16];
    const float* Wuco    = (const float*)d_in[17];
    const float* Wpco    = (const float*)d_in[18];
    const float* Wss     = (const float*)d_in[19];
    const float* bias    = (const float*)d_in[20];
    float* outp = (float*)d_out;

    char* ws = (char*)d_ws;
    size_t off = 0;
    auto carve = [&](size_t bytes) -> void* {
        off = (off + 255) & ~(size_t)255;
        void* p = ws + off;
        off += bytes;
        return p;
    };
    // total ~84 MB (proven-safe range)
    float* ufs = (float*)carve(4ll * 3 * BATCH * DIM);
    float* alt = (float*)carve(4ll * BATCH * NPOS);
    float* bst = (float*)carve(4ll * DIM * BATCH);
    int* rptr = (int*)carve(4 * (N_USERS + 1));
    int* cptr = (int*)carve(4 * (N_POIS + 1));
    int* cnts = (int*)carve(4 * (2 * (N_USERS + N_POIS)));
    int* rcnt = cnts;
    int* ccnt = cnts + N_USERS;
    int* rcur = ccnt + N_POIS;
    int* ccur = rcur + N_USERS;
    int* rcols = (int*)carve(4 * (size_t)N_EDGES);
    int* crows = (int*)carve(4 * (size_t)N_EDGES);
    float* rv[3]; float* cv[3];
    for (int c = 0; c < 3; c++) rv[c] = (float*)carve(4 * (size_t)N_EDGES);
    for (int c = 0; c < 3; c++) cv[c] = (float*)carve(4 * (size_t)N_EDGES);
    unsigned short* pid_h = (unsigned short*)carve(2ll * N_POIS * DIM);
    unsigned short* utr_h = (unsigned short*)carve(2ll * N_USERS * DIM);  // 10.24 MB; pf alias
    unsigned short* ptr_h = (unsigned short*)carve(2ll * N_POIS * DIM);
    float* su  = (float*)carve(4ll * N_USERS * DIM);   // cand alias
    float* sp  = (float*)carve(4ll * N_POIS * DIM);
    float* idf = (float*)carve(4ll * N_USERS * DIM);
    float* pf = (float*)utr_h;            // utr_h dead before pf written
    float* cand_s = su;                   // su dead before score_topk
    int*   cand_i = (int*)(su + (size_t)NCHUNK * BATCH * TOPK);

    zero_kernel<<<(2 * (N_USERS + N_POIS) + 255) / 256, 256, 0, stream>>>(
        (unsigned int*)cnts, 2 * (N_USERS + N_POIS));
    cast_f16_kernel<<<(N_POIS * DIM / 2 + 255) / 256, 256, 0, stream>>>(pid, pid_h, N_POIS * DIM / 2);
    hist_kernel<<<(N_EDGES + 255) / 256, 256, 0, stream>>>(er, ec, rcnt, ccnt);
    scan_kernel<<<2, 256, 0, stream>>>(rcnt, rptr, ccnt, cptr);
    fill_kernel<<<(N_EDGES + 255) / 256, 256, 0, stream>>>(
        er, ec, rptr, cptr, rcur, ccur, rcols, crows,
        click, favor, consume, rv[0], rv[1], rv[2], cv[0], cv[1], cv[2]);

    struct Ch { const float* Wu; const float* Wp; int wsel; int fsel; };
    // wn (softmax over w[1,3]):  favor=0, click=1, consume=2
    // fwn (softmax over fw[3,1]): favor=0, consume=1, click=2
    Ch chs[3] = { { Wuc,  Wpc,  1, 2 },     // ch0 = click
                  { Wufv, Wpfv, 0, 0 },     // ch1 = favor
                  { Wuco, Wpco, 2, 1 } };   // ch2 = consume

    for (int c = 0; c < 3; c++) {
        // layer 1: u1 = A p0 ; su = uid + n(u1).  p1 = A^T u1 ; sp = pid + n(p1)
        spmm_kernel<<<N_USERS * 64 / 256, 256, 0, stream>>>(rptr, rcols, rv[c], pid_h, utr_h, uid, su, N_USERS);
        spmm_kernel<<<N_POIS * 64 / 256, 256, 0, stream>>>(cptr, crows, cv[c], utr_h, ptr_h, pid, sp, N_POIS);
        // layer 2
        spmm_kernel<<<N_USERS * 64 / 256, 256, 0, stream>>>(rptr, rcols, rv[c], ptr_h, utr_h, su, su, N_USERS);
        spmm_kernel<<<N_POIS * 64 / 256, 256, 0, stream>>>(cptr, crows, cv[c], utr_h, ptr_h, sp, sp, N_POIS);
        // idf (+)= fwn_c * (su @ Wu^T)
        gemm_aw_kernel<<<N_USERS / 32, 256, 0, stream>>>(su, chs[c].Wu, nullptr, idf, fw3, chs[c].fsel, (c == 0) ? 1 : 0, N_USERS);
        ufsel_kernel<<<BATCH, 128, 0, stream>>>(su, chs[c].Wu, uidx, ufs + (size_t)c * BATCH * DIM);
        // pf = sp @ Wp^T  (pf aliases utr_h, dead after L2 poi hop)
        gemm_aw_kernel<<<N_POIS / 32, 256, 0, stream>>>(sp, chs[c].Wp, pf, nullptr, fw3, 0, 0, N_POIS);
        predict_kernel<<<BATCH * NPOS * 64 / 256, 256, 0, stream>>>(
            ufs + (size_t)c * BATCH * DIM, pf, pidx, w3, chs[c].wsel, (c == 0) ? 1 : 0, alt);
    }

    loss_kernel<<<1, 256, 0, stream>>>(alt, labels, outp);
    bs_kernel<<<BATCH, 128, 0, stream>>>(idf, Wss, bias, uidx, bst);
    dim3 sg(NCHUNK, 4);
    score_topk_kernel<<<sg, 256, 0, stream>>>(idf, bst, cand_s, cand_i);
    topk_merge_kernel<<<BATCH, 128, 0, stream>>>(cand_s, cand_i, guf, outp);
}